// Round 10
// baseline (842.895 us; speedup 1.0000x reference)
//
#include <hip/hip_runtime.h>
#include <cstdint>
#include <cstddef>

#define Bdim 8
#define Tdim 128
#define Sdim 256
#define Hdim 1024
#define Vdim 32000
#define SENT 0xFFFFFFFFFFFFFFFFULL

typedef unsigned short u16;
typedef unsigned long long u64;
typedef __attribute__((ext_vector_type(8))) short short8;
typedef __attribute__((ext_vector_type(4))) short short4v;
typedef __attribute__((ext_vector_type(4))) float f32x4;
typedef __attribute__((ext_vector_type(2))) unsigned long long u64x2;

union Frag { short8 v; short4v h[2]; };

__device__ __forceinline__ float bf2f(u16 u){
  union { unsigned int i; float f; } x; x.i = ((unsigned int)u) << 16; return x.f;
}
__device__ __forceinline__ u16 f2b(float f){
  union { float f; unsigned int u; } x; x.f = f;
  unsigned int r = x.u + 0x7FFFu + ((x.u >> 16) & 1u);  // RNE
  return (u16)(r >> 16);
}
__device__ __forceinline__ float ftanh(float x){
  x = fminf(10.f, fmaxf(-10.f, x));
  const float e = __expf(2.f * x);
  return (e - 1.f) / (e + 1.f);
}

__device__ __forceinline__ void gload16(const void* g, void* l){
  __builtin_amdgcn_global_load_lds((const __attribute__((address_space(1))) unsigned int*)g,
                                   (__attribute__((address_space(3))) unsigned int*)l, 16, 0, 0);
}

// 16B-cell swizzle for 64B-wide LDS tile rows (4 cells/row)
__device__ __forceinline__ int qsw(int r){ return (r + (r >> 2)) & 3; }

__device__ __forceinline__ u64 aload(const u64* p){
  return __hip_atomic_load(p, __ATOMIC_RELAXED, __HIP_MEMORY_SCOPE_AGENT);
}
__device__ __forceinline__ void astore(u64* p, u64 v){
  __hip_atomic_store(p, v, __ATOMIC_RELAXED, __HIP_MEMORY_SCOPE_AGENT);
}

__global__ __launch_bounds__(256) void detect_bool_k(const unsigned char* __restrict__ p, int* __restrict__ flag){
  __shared__ int s;
  if (threadIdx.x == 0) s = 0;
  __syncthreads();
  int loc = 0;
  for (int i = threadIdx.x; i < 65536; i += 256)
    if ((i & 3) && p[i]) loc = 1;
  if (loc) atomicOr(&s, 1);
  __syncthreads();
  if (threadIdx.x == 0) flag[0] = s;
}

__device__ __forceinline__ bool mask_at(const void* m, size_t idx, int byteflag){
  if (byteflag) return ((const unsigned char*)m)[idx] != 0;
  return ((const int*)m)[idx] != 0;
}

// ---------------- 2-phase double-buffered GEMM core
// MASK: 0 none, 1 runtime-dtype mask via mflag, 2 byte mask.
// NT: n-tiles (128 cols each) per block — NT=2 doubles MFMA per barrier.
template<typename OutT, bool BF32, int MASK, int NT>
__device__ __forceinline__ void gemm_core(
    char* ldsA0, char* ldsB0, char* ldsA1, char* ldsB1,
    int m0, int n0, int z,
    const u16* __restrict__ A, int lda, long sA,
    const void* __restrict__ Bp, int ldb, long sB,
    OutT* __restrict__ C, int ldc, long sC,
    const float* __restrict__ bias,
    const void* __restrict__ mask,
    const int* __restrict__ mflag,
    int K, float alpha)
{
  const int tid  = threadIdx.x;
  const int lane = tid & 63, wid = tid >> 6;
  const int lm = lane & 15, lg = lane >> 4;
  const int wm = wid >> 1, wn = wid & 1;            // 2x2 waves, 64x64 each
  const char* Ab = (const char*)(A + (size_t)z * sA);

  f32x4 acc[4][4 * NT];
#pragma unroll
  for (int i = 0; i < 4; i++)
#pragma unroll
    for (int j = 0; j < 4 * NT; j++) acc[i][j] = (f32x4){0.f, 0.f, 0.f, 0.f};

  const int brow = tid >> 1, bhalf = tid & 1;       // BF32 staging coords
  const int qb_st = qsw(brow);

  auto stageA = [&](char* dst, int k0){
    const char* ga = Ab + ((size_t)m0 * lda + k0) * 2;
    const int f0 = tid, f1 = tid + 256;
    const int r0 = f0 >> 2, r1 = f1 >> 2;
    gload16(ga + (size_t)r0 * (lda * 2) + ((f0 & 3) ^ qsw(r0)) * 16, dst + (f0 & ~63) * 16);
    gload16(ga + (size_t)r1 * (lda * 2) + ((f1 & 3) ^ qsw(r1)) * 16, dst + (f1 & ~63) * 16);
  };
  auto stageB16 = [&](char* dst, int k0){
    const char* gbase = (const char*)((const u16*)Bp + (size_t)z * sB);
#pragma unroll
    for (int s = 0; s < NT; s++) {
      const char* gb = gbase + ((size_t)(n0 + s * 128) * ldb + k0) * 2;
      const int f0 = tid, f1 = tid + 256;
      const int r0 = f0 >> 2, r1 = f1 >> 2;
      gload16(gb + (size_t)r0 * (ldb * 2) + ((f0 & 3) ^ qsw(r0)) * 16, dst + s * 8192 + (f0 & ~63) * 16);
      gload16(gb + (size_t)r1 * (ldb * 2) + ((f1 & 3) ^ qsw(r1)) * 16, dst + s * 8192 + (f1 & ~63) * 16);
    }
  };

  float4 nv0, nv1, nv2, nv3;                        // BF32 in-flight tile (NT=1 only)
  auto loadB32 = [&](int k0){
    const float* Bf = (const float*)Bp + (size_t)z * sB;
    const float4* src = (const float4*)(Bf + (size_t)(n0 + brow) * ldb + k0 + bhalf * 16);
    nv0 = src[0]; nv1 = src[1]; nv2 = src[2]; nv3 = src[3];
  };
  auto writeB32 = [&](char* dst){
    union { short8 v; short s[8]; } p0, p1;
    p0.s[0]=(short)f2b(nv0.x); p0.s[1]=(short)f2b(nv0.y); p0.s[2]=(short)f2b(nv0.z); p0.s[3]=(short)f2b(nv0.w);
    p0.s[4]=(short)f2b(nv1.x); p0.s[5]=(short)f2b(nv1.y); p0.s[6]=(short)f2b(nv1.z); p0.s[7]=(short)f2b(nv1.w);
    p1.s[0]=(short)f2b(nv2.x); p1.s[1]=(short)f2b(nv2.y); p1.s[2]=(short)f2b(nv2.z); p1.s[3]=(short)f2b(nv2.w);
    p1.s[4]=(short)f2b(nv3.x); p1.s[5]=(short)f2b(nv3.y); p1.s[6]=(short)f2b(nv3.z); p1.s[7]=(short)f2b(nv3.w);
    char* base = dst + brow * 64;
    *(short8*)(base + (((bhalf * 2 + 0) ^ qb_st) * 16)) = p0.v;
    *(short8*)(base + (((bhalf * 2 + 1) ^ qb_st) * 16)) = p1.v;
  };

  stageA(ldsA0, 0);
  if (BF32) { loadB32(0); writeB32(ldsB0); }
  else stageB16(ldsB0, 0);
  __syncthreads();

  char *cA = ldsA0, *cB = ldsB0, *nA = ldsA1, *nB = ldsB1;
  const int nk = K >> 5;
  for (int i = 0; i < nk; i++) {
    const bool more = (i + 1) < nk;
    if (more) {               // issue next-tile loads before compute (T3/T14)
      stageA(nA, (i + 1) << 5);
      if (BF32) loadB32((i + 1) << 5);
      else stageB16(nB, (i + 1) << 5);
    }
    Frag a[4];
#pragma unroll
    for (int mi = 0; mi < 4; mi++) {
      const int rr = wm * 64 + mi * 16 + lm;
      const int q = qsw(rr);
      const char* p = cA + rr * 64 + (lg & 1) * 8;
      a[mi].h[0] = *(const short4v*)(p + (((lg >> 1) ^ q) * 16));
      a[mi].h[1] = *(const short4v*)(p + ((((lg >> 1) | 2) ^ q) * 16));
    }
#pragma unroll
    for (int ni = 0; ni < 4 * NT; ni++) {
      const int s = ni >> 2, nl = ni & 3;
      const int rr = wn * 64 + nl * 16 + lm;
      const int q = qsw(rr);
      const char* p = cB + s * 8192 + rr * 64 + (lg & 1) * 8;
      Frag b;
      b.h[0] = *(const short4v*)(p + (((lg >> 1) ^ q) * 16));
      b.h[1] = *(const short4v*)(p + ((((lg >> 1) | 2) ^ q) * 16));
#pragma unroll
      for (int mi = 0; mi < 4; mi++)
        acc[mi][ni] = __builtin_amdgcn_mfma_f32_16x16x32_bf16(a[mi].v, b.v, acc[mi][ni], 0, 0, 0);
    }
    if (BF32 && more) writeB32(nB);    // convert-late
    __syncthreads();
    char* t;
    t = cA; cA = nA; nA = t;
    t = cB; cB = nB; nB = t;
  }

  const int bflag = (MASK == 1) ? *mflag : 0;
#pragma unroll
  for (int mi = 0; mi < 4; mi++) {
#pragma unroll
    for (int ni = 0; ni < 4 * NT; ni++) {
      const int row = m0 + wm * 64 + mi * 16 + lg * 4;
      const int col = n0 + (ni >> 2) * 128 + wn * 64 + (ni & 3) * 16 + lm;
      const float bb = bias ? bias[col] : 0.f;
#pragma unroll
      for (int j = 0; j < 4; j++) {
        float v = acc[mi][ni][j] * alpha + bb;
        const size_t midx = (size_t)(row + j) * ldc + col;
        if (MASK == 1) { if (!mask_at(mask, midx, bflag)) v = -10000.0f; }
        if (MASK == 2) { if (!((const unsigned char*)mask)[midx]) v = -10000.0f; }
        const size_t o = (size_t)z * sC + midx;
        if constexpr (sizeof(OutT) == 2) C[o] = (OutT)f2b(v); else C[o] = (OutT)v;
      }
    }
  }
}

template<typename OutT, bool BF32, int MASK, bool SWAP, int NT = 1>
__global__ __launch_bounds__(256) void gemm_bt(
    const u16* __restrict__ A, int lda, long sA,
    const void* __restrict__ Bp, int ldb, long sB,
    OutT* __restrict__ C, int ldc, long sC,
    const float* __restrict__ bias,
    const void* __restrict__ mask,
    const int* __restrict__ mflag,
    int K, float alpha)
{
  __shared__ alignas(16) char lds[(8192 + 8192 * NT) * 2];
  const int m0 = (SWAP ? blockIdx.x : blockIdx.y) * 128;
  const int n0 = (SWAP ? blockIdx.y : blockIdx.x) * (128 * NT);
  char* ldsA1 = lds + 8192 + 8192 * NT;
  gemm_core<OutT, BF32, MASK, NT>(lds, lds + 8192, ldsA1, ldsA1 + 8192,
      m0, n0, blockIdx.z, A, lda, sA, Bp, ldb, sB, C, ldc, sC,
      bias, mask, mflag, K, alpha);
}

// ---------------- persistent LSTM body: value-polled sync, swapped-operand MFMA
// mfma(whh_frag, h_frag, acc): D row = gate col (lg*4+j), D col = batch (lm).
// With gate-interleaved perm, lane (lg,lm) holds acc[j]=(i,f,g,o) of unit
// wid*4+lg, batch lm — cell update needs NO transpose, no g_lds, no hout.
// h gathered via 3 shfl and stored u64/lane directly to the packet.
__device__ void lstm_body(char* smem,
    const u16* __restrict__ xpre, const u16* __restrict__ whh,
    u16* __restrict__ hbuf, int bx)
{
  u16* wlds = (u16*)smem;                       // 64x1024, cell c^(r&7) swizzle
  u16* hlds = (u16*)(smem + 131072);            // 8x1024,  cell c^m swizzle
  const int tid = threadIdx.x, lane = tid & 63, wid = tid >> 6;
  const int lm = lane & 15, lg = lane >> 4;
  const int gcol0 = bx * 64;

  for (int q = tid; q < 8192; q += 256) {
    const int r = q >> 7, cc = q & 127;
    gload16(whh + (size_t)(gcol0 + r) * 1024 + (size_t)(cc ^ (r & 7)) * 8,
            (char*)wlds + (q & ~63) * 16);
  }

  float c_reg = 0.f;
  const int rloc = wid * 16 + lm, swb = rloc & 7, swa = lm & 7;
  const u16* wl = wlds + rloc * 1024;
  const u16* hl = hlds + swa * 1024;
  const int pk = tid >> 2, qq = tid & 3;            // consumer: packet, quarter
  // xpre: lane loads 4 consecutive gate cols (unit wid*4+lg) for batch lm
  const u16* xp = xpre + (size_t)(lm * Tdim) * 4096 + gcol0 + wid * 16 + lg * 4;

  for (int t = 0; t < Tdim; t++) {
    u64 xw = 0;
    if (lm < 8) xw = *(const u64*)(xp + (size_t)t * 4096);
    if (t > 0) {
      const u64* ps = (const u64*)(hbuf + ((size_t)(t - 1) * 64 + pk) * 128) + qq * 8;
      u64 w0=SENT,w1=SENT,w2=SENT,w3=SENT,w4=SENT,w5=SENT,w6=SENT,w7=SENT;
      for (;;) {
        if (w0 == SENT) w0 = aload(ps + 0);
        if (w1 == SENT) w1 = aload(ps + 1);
        if (w2 == SENT) w2 = aload(ps + 2);
        if (w3 == SENT) w3 = aload(ps + 3);
        if (w4 == SENT) w4 = aload(ps + 4);
        if (w5 == SENT) w5 = aload(ps + 5);
        if (w6 == SENT) w6 = aload(ps + 6);
        if (w7 == SENT) w7 = aload(ps + 7);
        if (w0 != SENT && w1 != SENT && w2 != SENT && w3 != SENT &&
            w4 != SENT && w5 != SENT && w6 != SENT && w7 != SENT) break;
        __builtin_amdgcn_s_sleep(1);
      }
      {
        const int m = qq * 2;
        u64x2 a; a[0] = w0; a[1] = w1;
        u64x2 b; b[0] = w2; b[1] = w3;
        *(u64x2*)((char*)hlds + m * 2048 + (((pk * 2 + 0) ^ m) * 16)) = a;
        *(u64x2*)((char*)hlds + m * 2048 + (((pk * 2 + 1) ^ m) * 16)) = b;
      }
      {
        const int m = qq * 2 + 1;
        u64x2 a; a[0] = w4; a[1] = w5;
        u64x2 b; b[0] = w6; b[1] = w7;
        *(u64x2*)((char*)hlds + m * 2048 + (((pk * 2 + 0) ^ m) * 16)) = a;
        *(u64x2*)((char*)hlds + m * 2048 + (((pk * 2 + 1) ^ m) * 16)) = b;
      }
    }
    __syncthreads();   // S2: hlds ready

    f32x4 acc0, acc1, acc2, acc3;
    {
      union { u64 w; u16 s[4]; } xu; xu.w = xw;
      acc0[0] = bf2f(xu.s[0]); acc0[1] = bf2f(xu.s[1]);
      acc0[2] = bf2f(xu.s[2]); acc0[3] = bf2f(xu.s[3]);
    }
    acc1 = (f32x4){0.f,0.f,0.f,0.f};
    acc2 = (f32x4){0.f,0.f,0.f,0.f};
    acc3 = (f32x4){0.f,0.f,0.f,0.f};

    if (t > 0) {
#pragma unroll
      for (int kk = 0; kk < 32; kk++) {
        const int c0 = kk * 4 + (lg >> 1);
        const int sub = (lg & 1) * 4;
        Frag aw, bh;
        aw.h[0] = *(const short4v*)(wl + ((c0 ^ swb) << 3) + sub);
        aw.h[1] = *(const short4v*)(wl + (((c0 + 2) ^ swb) << 3) + sub);
        bh.h[0] = *(const short4v*)(hl + ((c0 ^ swa) << 3) + sub);
        bh.h[1] = *(const short4v*)(hl + (((c0 + 2) ^ swa) << 3) + sub);
        if ((kk & 3) == 0)      acc0 = __builtin_amdgcn_mfma_f32_16x16x32_bf16(aw.v, bh.v, acc0, 0, 0, 0);
        else if ((kk & 3) == 1) acc1 = __builtin_amdgcn_mfma_f32_16x16x32_bf16(aw.v, bh.v, acc1, 0, 0, 0);
        else if ((kk & 3) == 2) acc2 = __builtin_amdgcn_mfma_f32_16x16x32_bf16(aw.v, bh.v, acc2, 0, 0, 0);
        else                    acc3 = __builtin_amdgcn_mfma_f32_16x16x32_bf16(aw.v, bh.v, acc3, 0, 0, 0);
      }
    }
    const f32x4 g4 = (acc0 + acc1) + (acc2 + acc3);  // i,f,g,o for (batch lm, unit wid*4+lg)

    const float si = 1.f / (1.f + __expf(-g4[0]));
    const float sf = 1.f / (1.f + __expf(-g4[1]));
    const float so = 1.f / (1.f + __expf(-g4[3]));
    const float cn = sf * c_reg + si * ftanh(g4[2]);
    c_reg = cn;
    const float hn = so * ftanh(cn);
    const int hb = (int)f2b(hn);

    // gather units wid*4+0..3 of batch lm from lanes lm, lm+16, lm+32, lm+48
    const int v0 = __shfl(hb, lm, 64);
    const int v1 = __shfl(hb, lm + 16, 64);
    const int v2 = __shfl(hb, lm + 32, 64);
    const int v3 = __shfl(hb, lm + 48, 64);
    if (lg == 0 && lm < 8) {
      const u64 pack = (u64)(v0 & 0xFFFF) | ((u64)(v1 & 0xFFFF) << 16)
                     | ((u64)(v2 & 0xFFFF) << 32) | ((u64)(v3 & 0xFFFF) << 48);
      astore((u64*)(hbuf + ((size_t)t * 64 + bx) * 128 + lm * 16 + wid * 4), pack);
    }
    __syncthreads();   // S5: hlds reads done before next step's copy overwrites
  }
}

// blocks 0..63: LSTM; 64..191: k-projection GEMM; 192..255: streamers
// (wo fp32->bf16 convert + pattern_mask byte-pack) hidden under the LSTM.
__global__ __launch_bounds__(256) void lstm_plus(
    const u16* __restrict__ xpre, const u16* __restrict__ whh,
    u16* __restrict__ hbuf,
    const u16* __restrict__ encb, const u16* __restrict__ wkb,
    float* __restrict__ klin, const float* __restrict__ bk,
    const float* __restrict__ wo, u16* __restrict__ wob,
    const void* __restrict__ pmask, unsigned char* __restrict__ pmaskb,
    const int* __restrict__ bflag)
{
  __shared__ alignas(16) char smem[147456];
  const int bx = blockIdx.x;
  if (bx < 64) {
    lstm_body(smem, xpre, whh, hbuf, bx);
  } else if (bx < 192) {
    const int idx = bx - 64;               // 16 m-tiles x 8 n-tiles
    gemm_core<float, false, 0, 1>(smem, smem + 8192, smem + 16384, smem + 24576,
        (idx >> 3) * 128, (idx & 7) * 128, 0,
        encb, 1024, 0, wkb, 1024, 0, klin, 1024, 0, bk, nullptr, nullptr, 1024, 1.f);
  } else {
    const int s = bx - 192;                // 0..63
    const int tid = threadIdx.x;
    if (wob) {
      for (int r = s; r < Vdim; r += 64) {
        const size_t i = (size_t)r * 1024 + tid * 4;
        const float4 v = *(const float4*)(wo + i);
        u16* op = wob + i;
        op[0] = f2b(v.x); op[1] = f2b(v.y); op[2] = f2b(v.z); op[3] = f2b(v.w);
      }
    }
    if (pmaskb) {
      const int bfl = *bflag;
      const size_t total = (size_t)Bdim * Tdim * Vdim;       // 32,768,000
      const size_t nthr = 64 * 256;
      if (bfl == 0) {     // int32 bools -> bytes
        for (size_t i = ((size_t)s * 256 + tid) * 4; i < total; i += nthr * 4) {
          const int4 v = *(const int4*)((const int*)pmask + i);
          uchar4 o;
          o.x = v.x ? 1 : 0; o.y = v.y ? 1 : 0; o.z = v.z ? 1 : 0; o.w = v.w ? 1 : 0;
          *(uchar4*)(pmaskb + i) = o;
        }
      } else {            // already bytes -> copy 16B
        for (size_t i = ((size_t)s * 256 + tid) * 16; i < total; i += nthr * 16) {
          *(int4*)(pmaskb + i) = *(const int4*)((const unsigned char*)pmask + i);
        }
      }
    }
  }
}

// hbuf [t][p][m][u16x16] -> cat rows (m*Tdim+t), cols p*16.. (left half of 2048)
__global__ __launch_bounds__(256) void hbuf_cat_k(const u16* __restrict__ hbuf, u16* __restrict__ cat){
  const int t = blockIdx.x, tid = threadIdx.x;
  const int p = tid >> 2, q = tid & 3;
  const u64* src = (const u64*)(hbuf + ((size_t)t * 64 + p) * 128);
#pragma unroll
  for (int m = 0; m < 8; m++) {
    const u64 v = src[m * 4 + q];
    *(u64*)(cat + (size_t)(m * Tdim + t) * 2048 + p * 16 + q * 4) = v;
  }
}

// ---------------- fused prep: weight converts + embed + bias + hbuf sentinel
__global__ __launch_bounds__(256) void prep_k(
    const float* __restrict__ w_hh, const float* __restrict__ w_ih,
    const float* __restrict__ wq,   const float* __restrict__ wk,
    const float* __restrict__ wc,   const float* __restrict__ enc,
    const int* __restrict__ ids,
    const float* __restrict__ tok,  const float* __restrict__ pos,
    const float* __restrict__ b_ih, const float* __restrict__ b_hh,
    u16* __restrict__ whhb, u16* __restrict__ wihb,
    u16* __restrict__ wqb,  u16* __restrict__ wkb,  u16* __restrict__ wcb,
    u16* __restrict__ encb, u16* __restrict__ xbf,
    float* __restrict__ biasf, u64* __restrict__ hbuf)
{
  const int b = blockIdx.x, tid = threadIdx.x;
  if (b < 8192) {                        // gate-permuted whh / w_ih rows
    const bool ih = b >= 4096;
    const int r = b & 4095;
    const int p = (r & 3) * Hdim + (r >> 2);
    const float4 v = *(const float4*)((ih ? w_ih : w_hh) + (size_t)p * Hdim + tid * 4);
    u16* op = (ih ? wihb : whhb) + (size_t)r * Hdim + tid * 4;
    op[0] = f2b(v.x); op[1] = f2b(v.y); op[2] = f2b(v.z); op[3] = f2b(v.w);
  } else if (b < 9216) {
    const size_t i = (size_t)(b - 8192) * 1024 + tid * 4;
    const float4 v = *(const float4*)(wq + i);
    u16* op = wqb + i;
    op[0] = f2b(v.x); op[1] = f2b(v.y); op[2] = f2b(v.z); op[3] = f2b(v.w);
  } else if (b < 10240) {
    const size_t i = (size_t)(b - 9216) * 1024 + tid * 4;
    const float4 v = *(const float4*)(wk + i);
    u16* op = wkb + i;
    op[0] = f2b(v.x); op[1] = f2b(v.y); op[2] = f2b(v.z); op[3] = f2b(v.w);
  } else if (b < 12288) {
    const size_t i = (size_t)(b - 10240) * 1024 + tid * 4;
    const float4 v = *(const float4*)(wc + i);
    u16* op = wcb + i;
    op[0] = f2b(v.x); op[1] = f2b(v.y); op[2] = f2b(v.z); op[3] = f2b(v.w);
  } else if (b < 14336) {
    const size_t i = (size_t)(b - 12288) * 1024 + tid * 4;
    const float4 v = *(const float4*)(enc + i);
    u16* op = encb + i;
    op[0] = f2b(v.x); op[1] = f2b(v.y); op[2] = f2b(v.z); op[3] = f2b(v.w);
  } else if (b < 15360) {                // embed
    const int row = b - 14336;
    const int t = row & (Tdim - 1);
    const int id = ids[row];
    const int h0 = tid * 4;
    const float4 a = *(const float4*)(tok + (size_t)id * Hdim + h0);
    const float4 p = *(const float4*)(pos + (size_t)t * Hdim + h0);
    u16* op = xbf + (size_t)row * Hdim + h0;
    op[0] = f2b(a.x + p.x); op[1] = f2b(a.y + p.y); op[2] = f2b(a.z + p.z); op[3] = f2b(a.w + p.w);
  } else if (b < 15364) {                // bias fold (gate-permuted)
    const int n0 = (b - 15360) * 1024 + tid * 4;
#pragma unroll
    for (int j = 0; j < 4; j++) {
      const int n = n0 + j;
      const int p = (n & 3) * Hdim + (n >> 2);
      biasf[n] = b_ih[p] + b_hh[p];
    }
  } else {                               // hbuf sentinel: 256 blocks x 256 thr x 4 u64
    const size_t i = ((size_t)(b - 15364) * 256 + tid) * 4;
    u64x2 s2; s2[0] = SENT; s2[1] = SENT;
    *(u64x2*)(hbuf + i)     = s2;
    *(u64x2*)(hbuf + i + 2) = s2;
  }
}

// ---------------- small kernels
__global__ __launch_bounds__(256) void ln_rows(const float* __restrict__ in, u16* __restrict__ out,
                                               const float* __restrict__ g, const float* __restrict__ be){
  const int row = blockIdx.x, tid = threadIdx.x;
  const int lane = tid & 63, wid = tid >> 6;
  const float4 x = *(const float4*)(in + (size_t)row * Hdim + tid * 4);
  float s = x.x + x.y + x.z + x.w;
  float q = x.x * x.x + x.y * x.y + x.z * x.z + x.w * x.w;
  for (int o = 32; o; o >>= 1) { s += __shfl_down(s, o, 64); q += __shfl_down(q, o, 64); }
  __shared__ float sm[8];
  if (lane == 0) { sm[wid] = s; sm[4 + wid] = q; }
  __syncthreads();
  const float ts = sm[0] + sm[1] + sm[2] + sm[3];
  const float tq = sm[4] + sm[5] + sm[6] + sm[7];
  const float mean = ts * (1.f / Hdim);
  const float var  = tq * (1.f / Hdim) - mean * mean;
  const float r = rsqrtf(var + 1e-5f);
  const int h0 = tid * 4;
  const float4 gv = *(const float4*)(g + h0);
  const float4 bv = *(const float4*)(be + h0);
  u16* op = out + (size_t)row * Hdim + h0;
  op[0] = f2b((x.x - mean) * r * gv.x + bv.x);
  op[1] = f2b((x.y - mean) * r * gv.y + bv.y);
  op[2] = f2b((x.z - mean) * r * gv.z + bv.z);
  op[3] = f2b((x.w - mean) * r * gv.w + bv.w);
}
__global__ __launch_bounds__(256) void softmax_k(const float* __restrict__ sc, const void* __restrict__ am,
                                                 const int* __restrict__ mflag, u16* __restrict__ w){
  const int row = blockIdx.x, tid = threadIdx.x;
  const int lane = tid & 63, wid = tid >> 6;
  const int b = row >> 7;
  const int bflag = *mflag;
  const float v = sc[(size_t)row * Sdim + tid];
  const bool mk = mask_at(am, (size_t)b * Sdim + tid, bflag);
  const float vm = mk ? v : -10000.0f;
  float mx = vm;
  for (int o = 32; o; o >>= 1) mx = fmaxf(mx, __shfl_down(mx, o, 64));
  __shared__ float sm[8];
  if (lane == 0) sm[wid] = mx;
  __syncthreads();
  mx = fmaxf(fmaxf(sm[0], sm[1]), fmaxf(sm[2], sm[3]));
  const float ex = mk ? expf(vm - mx) : 0.f;
  float ss = ex;
  for (int o = 32; o; o >>= 1) ss += __shfl_down(ss, o, 64);
  if (lane == 0) sm[4 + wid] = ss;
  __syncthreads();
  const float tot = sm[4] + sm[5] + sm[6] + sm[7];
  w[(size_t)row * Sdim + tid] = f2b(ex / (tot + 1e-6f));
}
__global__ __launch_bounds__(256) void transp_k(const u16* __restrict__ kn, u16* __restrict__ knT){
  __shared__ u16 tile[64][65];
  const int b = blockIdx.z, h0 = blockIdx.x * 64, s0 = blockIdx.y * 64;
  const u16* src = kn  + (size_t)b * Sdim * Hdim;
  u16* dst       = knT + (size_t)b * Hdim * Sdim;
  for (int e = threadIdx.x; e < 4096; e += 256) {
    const int r = e >> 6, c = e & 63;
    tile[r][c] = src[(size_t)(s0 + r) * Hdim + h0 + c];
  }
  __syncthreads();
  for (int e = threadIdx.x; e < 4096; e += 256) {
    const int hr = e >> 6, scc = e & 63;
    dst[(size_t)(h0 + hr) * Sdim + s0 + scc] = tile[scc][hr];
  }
}

extern "C" void kernel_launch(void* const* d_in, const int* in_sizes, int n_in,
                              void* d_out, int out_size, void* d_ws, size_t ws_size,
                              hipStream_t stream) {
  const int*   input_ids = (const int*)d_in[0];
  const float* enc   = (const float*)d_in[1];
  const void*  pmask = d_in[2];
  const void*  amask = d_in[3];
  const float* tok  = (const float*)d_in[4];
  const float* pos  = (const float*)d_in[5];
  const float* w_ih = (const float*)d_in[6];
  const float* w_hh = (const float*)d_in[7];
  const float* b_ih = (const float*)d_in[8];
  const float* b_hh = (const float*)d_in[9];
  const float* wq = (const float*)d_in[10];
  const float* bq = (const float*)d_in[11];
  const float* wk = (const float*)d_in[12];
  const float* bk = (const float*)d_in[13];
  const float* wc = (const float*)d_in[14];
  const float* bc = (const float*)d_in[15];
  const float* wo = (const float*)d_in[16];
  const float* bo = (const float*)d_in[17];
  const float* g1  = (const float*)d_in[18];
  const float* be1 = (const float*)d_in[19];
  const float* g2  = (const float*)d_in[20];
  const float* be2 = (const float*)d_in[21];
  float* out = (float*)d_out;

  char* ws = (char*)d_ws;
  size_t off = 0;
  auto alloc = [&](size_t b){ size_t o = off; off += (b + 255) & ~(size_t)255; return o; };
  u16*   whhb  = (u16*)  (ws + alloc((size_t)4096 * 1024 * 2));
  u16*   wihb  = (u16*)  (ws + alloc((size_t)4096 * 1024 * 2));
  u16*   wqb   = (u16*)  (ws + alloc((size_t)1024 * 1024 * 2));
  u16*   wkb   = (u16*)  (ws + alloc((size_t)1024 * 1024 * 2));
  u16*   wcb   = (u16*)  (ws + alloc((size_t)1024 * 2048 * 2));
  float* biasf = (float*)(ws + alloc(4096 * 4));
  u16*   xbf   = (u16*)  (ws + alloc((size_t)1024 * 1024 * 2));
  u16*   encb  = (u16*)  (ws + alloc((size_t)2048 * 1024 * 2));
  u16*   xpre  = (u16*)  (ws + alloc((size_t)1024 * 4096 * 2));
  u16*   hbuf  = (u16*)  (ws + alloc((size_t)Tdim * 64 * 128 * 2));
  u16*   cat   = (u16*)  (ws + alloc((size_t)1024 * 2048 * 2));
  float* qlin  = (float*)(ws + alloc((size_t)1024 * 1024 * 4));
  u16*   qn    = (u16*)  (ws + alloc((size_t)1024 * 1024 * 2));
  float* klin  = (float*)(ws + alloc((size_t)2048 * 1024 * 4));
  u16*   kn    = (u16*)  (ws + alloc((size_t)2048 * 1024 * 2));
  u16*   knT   = (u16*)  (ws + alloc((size_t)2048 * 1024 * 2));
  float* scores= (float*)(ws + alloc((size_t)8 * 128 * 256 * 4));
  u16*   attw  = (u16*)  (ws + alloc((size_t)8 * 128 * 256 * 2));
  float* hlin  = (float*)(ws + alloc((size_t)1024 * 1024 * 4));
  u16*   hid   = (u16*)  (ws + alloc((size_t)1024 * 1024 * 2));
  int*   bflag = (int*)  (ws + alloc(256));
  unsigned char* pmaskb = (unsigned char*)(ws + alloc((size_t)Bdim * Tdim * Vdim));
  const bool havePak = off <= ws_size;
  u16*   wob   = (u16*)  (ws + alloc((size_t)Vdim * Hdim * 2));
  const bool haveWob = off <= ws_size;
  if (!havePak) pmaskb = nullptr;
  if (!haveWob) wob = nullptr;
  (void)in_sizes; (void)n_in; (void)out_size;

  detect_bool_k<<<1, 256, 0, stream>>>((const unsigned char*)pmask, bflag);
  prep_k<<<15620, 256, 0, stream>>>(w_hh, w_ih, wq, wk, wc, enc, input_ids,
      tok, pos, b_ih, b_hh, whhb, wihb, wqb, wkb, wcb, encb, xbf, biasf, (u64*)hbuf);

  // x_pre = x @ w_ih_perm.T + (b_ih + b_hh)   -> bf16 (1024 x 4096)
  gemm_bt<u16, false, 0, false><<<dim3(32, 8, 1), 256, 0, stream>>>(
      xbf, 1024, 0, wihb, 1024, 0, xpre, 4096, 0, biasf, nullptr, nullptr, 1024, 1.f);

  // LSTM (0-63) + k-projection (64-191) + wo/mask streamers (192-255)
  lstm_plus<<<256, 256, 0, stream>>>(xpre, whhb, hbuf, encb, wkb, klin, bk,
                                     wo, wob, pmask, pmaskb, bflag);
  hbuf_cat_k<<<Tdim, 256, 0, stream>>>(hbuf, cat);

  // q = lstm_out @ wq.T + bq ; LN(g1,be1)
  gemm_bt<float, false, 0, false><<<dim3(8, 8, 1), 256, 0, stream>>>(
      cat, 2048, 0, wqb, 1024, 0, qlin, 1024, 0, bq, nullptr, nullptr, 1024, 1.f);
  ln_rows<<<1024, 256, 0, stream>>>(qlin, qn, g1, be1);
  ln_rows<<<2048, 256, 0, stream>>>(klin, kn, g1, be1);
  transp_k<<<dim3(16, 4, 8), 256, 0, stream>>>(kn, knT);

  // scores = qn @ kn^T * scale   (batched over 8)
  gemm_bt<float, false, 0, false><<<dim3(2, 1, 8), 256, 0, stream>>>(
      qn, 1024, 131072, kn, 1024, 262144, scores, 256, 32768, nullptr, nullptr, nullptr, 1024, 0.015625f);
  softmax_k<<<1024, 256, 0, stream>>>(scores, amask, bflag, attw);
  // ctx = w @ kn  -> right half of cat   (batched)
  gemm_bt<u16, false, 0, false><<<dim3(8, 1, 8), 256, 0, stream>>>(
      attw, 256, 32768, knT, 256, 262144, cat + 1024, 2048, 262144, nullptr, nullptr, nullptr, 256, 1.f);

  // hidden = LN( cat @ wc.T + bc ; g2,be2 )
  gemm_bt<float, false, 0, false><<<dim3(8, 8, 1), 256, 0, stream>>>(
      cat, 2048, 0, wcb, 2048, 0, hlin, 1024, 0, bc, nullptr, nullptr, 2048, 1.f);
  ln_rows<<<1024, 256, 0, stream>>>(hlin, hid, g2, be2);

  // logits = hidden @ wo.T + bo, masked — SWAP grid + NT=2 (128x256 per block)
  if (wob && pmaskb)
    gemm_bt<float, false, 2, true, 2><<<dim3(8, 125, 1), 256, 0, stream>>>(
        hid, 1024, 0, wob, 1024, 0, out, 32000, 0, bo, pmaskb, nullptr, 1024, 1.f);
  else if (wob)
    gemm_bt<float, false, 1, true, 2><<<dim3(8, 125, 1), 256, 0, stream>>>(
        hid, 1024, 0, wob, 1024, 0, out, 32000, 0, bo, pmask, bflag, 1024, 1.f);
  else
    gemm_bt<float, true, 1, true><<<dim3(8, 250, 1), 256, 0, stream>>>(
        hid, 1024, 0, wo, 1024, 0, out, 32000, 0, bo, pmask, bflag, 1024, 1.f);
}

// Round 11
// 800.618 us; speedup vs baseline: 1.0528x; 1.0528x over previous
//
#include <hip/hip_runtime.h>
#include <cstdint>
#include <cstddef>

#define Bdim 8
#define Tdim 128
#define Sdim 256
#define Hdim 1024
#define Vdim 32000
#define SENT 0xFFFFFFFFFFFFFFFFULL

typedef unsigned short u16;
typedef unsigned long long u64;
typedef __attribute__((ext_vector_type(8))) short short8;
typedef __attribute__((ext_vector_type(4))) short short4v;
typedef __attribute__((ext_vector_type(4))) float f32x4;
typedef __attribute__((ext_vector_type(2))) unsigned long long u64x2;

union Frag { short8 v; short4v h[2]; };

__device__ __forceinline__ float bf2f(u16 u){
  union { unsigned int i; float f; } x; x.i = ((unsigned int)u) << 16; return x.f;
}
__device__ __forceinline__ u16 f2b(float f){
  union { float f; unsigned int u; } x; x.f = f;
  unsigned int r = x.u + 0x7FFFu + ((x.u >> 16) & 1u);  // RNE
  return (u16)(r >> 16);
}
__device__ __forceinline__ float ftanh(float x){
  x = fminf(10.f, fmaxf(-10.f, x));
  const float e = __expf(2.f * x);
  return (e - 1.f) / (e + 1.f);
}

__device__ __forceinline__ void gload16(const void* g, void* l){
  __builtin_amdgcn_global_load_lds((const __attribute__((address_space(1))) unsigned int*)g,
                                   (__attribute__((address_space(3))) unsigned int*)l, 16, 0, 0);
}

// 16B-cell swizzle for 64B-wide LDS tile rows (4 cells/row)
__device__ __forceinline__ int qsw(int r){ return (r + (r >> 2)) & 3; }

__device__ __forceinline__ u64 aload(const u64* p){
  return __hip_atomic_load(p, __ATOMIC_RELAXED, __HIP_MEMORY_SCOPE_AGENT);
}
__device__ __forceinline__ void astore(u64* p, u64 v){
  __hip_atomic_store(p, v, __ATOMIC_RELAXED, __HIP_MEMORY_SCOPE_AGENT);
}

__device__ __forceinline__ bool mask_at(const void* m, size_t idx, int byteflag){
  if (byteflag) return ((const unsigned char*)m)[idx] != 0;
  return ((const int*)m)[idx] != 0;
}

// ---------------- 2-phase double-buffered GEMM core
// MASK: 0 none, 1 runtime-dtype mask via mflag, 2 byte mask.  NT: n-tiles/block.
template<typename OutT, bool BF32, int MASK, int NT>
__device__ __forceinline__ void gemm_core(
    char* ldsA0, char* ldsB0, char* ldsA1, char* ldsB1,
    int m0, int n0, int z,
    const u16* __restrict__ A, int lda, long sA,
    const void* __restrict__ Bp, int ldb, long sB,
    OutT* __restrict__ C, int ldc, long sC,
    const float* __restrict__ bias,
    const void* __restrict__ mask,
    const int* __restrict__ mflag,
    int K, float alpha)
{
  const int tid  = threadIdx.x;
  const int lane = tid & 63, wid = tid >> 6;
  const int lm = lane & 15, lg = lane >> 4;
  const int wm = wid >> 1, wn = wid & 1;            // 2x2 waves, 64x64 each
  const char* Ab = (const char*)(A + (size_t)z * sA);

  f32x4 acc[4][4 * NT];
#pragma unroll
  for (int i = 0; i < 4; i++)
#pragma unroll
    for (int j = 0; j < 4 * NT; j++) acc[i][j] = (f32x4){0.f, 0.f, 0.f, 0.f};

  const int brow = tid >> 1, bhalf = tid & 1;       // BF32 staging coords
  const int qb_st = qsw(brow);

  auto stageA = [&](char* dst, int k0){
    const char* ga = Ab + ((size_t)m0 * lda + k0) * 2;
    const int f0 = tid, f1 = tid + 256;
    const int r0 = f0 >> 2, r1 = f1 >> 2;
    gload16(ga + (size_t)r0 * (lda * 2) + ((f0 & 3) ^ qsw(r0)) * 16, dst + (f0 & ~63) * 16);
    gload16(ga + (size_t)r1 * (lda * 2) + ((f1 & 3) ^ qsw(r1)) * 16, dst + (f1 & ~63) * 16);
  };
  auto stageB16 = [&](char* dst, int k0){
    const char* gbase = (const char*)((const u16*)Bp + (size_t)z * sB);
#pragma unroll
    for (int s = 0; s < NT; s++) {
      const char* gb = gbase + ((size_t)(n0 + s * 128) * ldb + k0) * 2;
      const int f0 = tid, f1 = tid + 256;
      const int r0 = f0 >> 2, r1 = f1 >> 2;
      gload16(gb + (size_t)r0 * (ldb * 2) + ((f0 & 3) ^ qsw(r0)) * 16, dst + s * 8192 + (f0 & ~63) * 16);
      gload16(gb + (size_t)r1 * (ldb * 2) + ((f1 & 3) ^ qsw(r1)) * 16, dst + s * 8192 + (f1 & ~63) * 16);
    }
  };

  float4 nv0, nv1, nv2, nv3;                        // BF32 in-flight tile (NT=1 only)
  auto loadB32 = [&](int k0){
    const float* Bf = (const float*)Bp + (size_t)z * sB;
    const float4* src = (const float4*)(Bf + (size_t)(n0 + brow) * ldb + k0 + bhalf * 16);
    nv0 = src[0]; nv1 = src[1]; nv2 = src[2]; nv3 = src[3];
  };
  auto writeB32 = [&](char* dst){
    union { short8 v; short s[8]; } p0, p1;
    p0.s[0]=(short)f2b(nv0.x); p0.s[1]=(short)f2b(nv0.y); p0.s[2]=(short)f2b(nv0.z); p0.s[3]=(short)f2b(nv0.w);
    p0.s[4]=(short)f2b(nv1.x); p0.s[5]=(short)f2b(nv1.y); p0.s[6]=(short)f2b(nv1.z); p0.s[7]=(short)f2b(nv1.w);
    p1.s[0]=(short)f2b(nv2.x); p1.s[1]=(short)f2b(nv2.y); p1.s[2]=(short)f2b(nv2.z); p1.s[3]=(short)f2b(nv2.w);
    p1.s[4]=(short)f2b(nv3.x); p1.s[5]=(short)f2b(nv3.y); p1.s[6]=(short)f2b(nv3.z); p1.s[7]=(short)f2b(nv3.w);
    char* base = dst + brow * 64;
    *(short8*)(base + (((bhalf * 2 + 0) ^ qb_st) * 16)) = p0.v;
    *(short8*)(base + (((bhalf * 2 + 1) ^ qb_st) * 16)) = p1.v;
  };

  stageA(ldsA0, 0);
  if (BF32) { loadB32(0); writeB32(ldsB0); }
  else stageB16(ldsB0, 0);
  __syncthreads();

  char *cA = ldsA0, *cB = ldsB0, *nA = ldsA1, *nB = ldsB1;
  const int nk = K >> 5;
  for (int i = 0; i < nk; i++) {
    const bool more = (i + 1) < nk;
    if (more) {               // issue next-tile loads before compute (T3/T14)
      stageA(nA, (i + 1) << 5);
      if (BF32) loadB32((i + 1) << 5);
      else stageB16(nB, (i + 1) << 5);
    }
    Frag a[4];
#pragma unroll
    for (int mi = 0; mi < 4; mi++) {
      const int rr = wm * 64 + mi * 16 + lm;
      const int q = qsw(rr);
      const char* p = cA + rr * 64 + (lg & 1) * 8;
      a[mi].h[0] = *(const short4v*)(p + (((lg >> 1) ^ q) * 16));
      a[mi].h[1] = *(const short4v*)(p + ((((lg >> 1) | 2) ^ q) * 16));
    }
#pragma unroll
    for (int ni = 0; ni < 4 * NT; ni++) {
      const int s = ni >> 2, nl = ni & 3;
      const int rr = wn * 64 + nl * 16 + lm;
      const int q = qsw(rr);
      const char* p = cB + s * 8192 + rr * 64 + (lg & 1) * 8;
      Frag b;
      b.h[0] = *(const short4v*)(p + (((lg >> 1) ^ q) * 16));
      b.h[1] = *(const short4v*)(p + ((((lg >> 1) | 2) ^ q) * 16));
#pragma unroll
      for (int mi = 0; mi < 4; mi++)
        acc[mi][ni] = __builtin_amdgcn_mfma_f32_16x16x32_bf16(a[mi].v, b.v, acc[mi][ni], 0, 0, 0);
    }
    if (BF32 && more) writeB32(nB);    // convert-late
    __syncthreads();
    char* t;
    t = cA; cA = nA; nA = t;
    t = cB; cB = nB; nB = t;
  }

  const int bflag = (MASK == 1) ? *mflag : 0;
#pragma unroll
  for (int mi = 0; mi < 4; mi++) {
#pragma unroll
    for (int ni = 0; ni < 4 * NT; ni++) {
      const int row = m0 + wm * 64 + mi * 16 + lg * 4;
      const int col = n0 + (ni >> 2) * 128 + wn * 64 + (ni & 3) * 16 + lm;
      const float bb = bias ? bias[col] : 0.f;
#pragma unroll
      for (int j = 0; j < 4; j++) {
        float v = acc[mi][ni][j] * alpha + bb;
        const size_t midx = (size_t)(row + j) * ldc + col;
        if (MASK == 1) { if (!mask_at(mask, midx, bflag)) v = -10000.0f; }
        if (MASK == 2) { if (!((const unsigned char*)mask)[midx]) v = -10000.0f; }
        const size_t o = (size_t)z * sC + midx;
        if constexpr (sizeof(OutT) == 2) C[o] = (OutT)f2b(v); else C[o] = (OutT)v;
      }
    }
  }
}

template<typename OutT, bool BF32, int MASK, bool SWAP, int NT = 1>
__global__ __launch_bounds__(256) void gemm_bt(
    const u16* __restrict__ A, int lda, long sA,
    const void* __restrict__ Bp, int ldb, long sB,
    OutT* __restrict__ C, int ldc, long sC,
    const float* __restrict__ bias,
    const void* __restrict__ mask,
    const int* __restrict__ mflag,
    int K, float alpha)
{
  __shared__ alignas(16) char lds[(8192 + 8192 * NT) * 2];
  const int m0 = (SWAP ? blockIdx.x : blockIdx.y) * 128;
  const int n0 = (SWAP ? blockIdx.y : blockIdx.x) * (128 * NT);
  char* ldsA1 = lds + 8192 + 8192 * NT;
  gemm_core<OutT, BF32, MASK, NT>(lds, lds + 8192, ldsA1, ldsA1 + 8192,
      m0, n0, blockIdx.z, A, lda, sA, Bp, ldb, sB, C, ldc, sC,
      bias, mask, mflag, K, alpha);
}

// ---------------- persistent LSTM body: value-polled sync, swapped-operand MFMA
// mfma(whh_frag, h_frag, acc): D row = gate col (lg*4+j), D col = batch (lm).
// Lane (lg,lm) holds acc[j]=(i,f,g,o) of unit wid*4+lg, batch lm — no transpose.
// h gathered via 3 shfl, stored u64/lane to hbuf packet AND directly into cat
// (fire-and-forget: no vmcnt in loop, so the extra store is free).
__device__ void lstm_body(char* smem,
    const u16* __restrict__ xpre, const u16* __restrict__ whh,
    u16* __restrict__ hbuf, u16* __restrict__ cat, int bx)
{
  u16* wlds = (u16*)smem;                       // 64x1024, cell c^(r&7) swizzle
  u16* hlds = (u16*)(smem + 131072);            // 8x1024,  cell c^m swizzle
  const int tid = threadIdx.x, lane = tid & 63, wid = tid >> 6;
  const int lm = lane & 15, lg = lane >> 4;
  const int gcol0 = bx * 64;

  for (int q = tid; q < 8192; q += 256) {
    const int r = q >> 7, cc = q & 127;
    gload16(whh + (size_t)(gcol0 + r) * 1024 + (size_t)(cc ^ (r & 7)) * 8,
            (char*)wlds + (q & ~63) * 16);
  }

  float c_reg = 0.f;
  const int rloc = wid * 16 + lm, swb = rloc & 7, swa = lm & 7;
  const u16* wl = wlds + rloc * 1024;
  const u16* hl = hlds + swa * 1024;
  const int pk = tid >> 2, qq = tid & 3;            // consumer: packet, quarter
  // xpre: lane loads 4 consecutive gate cols (unit wid*4+lg) for batch lm
  const u16* xp = xpre + (size_t)(lm * Tdim) * 4096 + gcol0 + wid * 16 + lg * 4;

  for (int t = 0; t < Tdim; t++) {
    u64 xw = 0;
    if (lm < 8) xw = *(const u64*)(xp + (size_t)t * 4096);
    if (t > 0) {
      const u64* ps = (const u64*)(hbuf + ((size_t)(t - 1) * 64 + pk) * 128) + qq * 8;
      u64 w0=SENT,w1=SENT,w2=SENT,w3=SENT,w4=SENT,w5=SENT,w6=SENT,w7=SENT;
      for (;;) {
        if (w0 == SENT) w0 = aload(ps + 0);
        if (w1 == SENT) w1 = aload(ps + 1);
        if (w2 == SENT) w2 = aload(ps + 2);
        if (w3 == SENT) w3 = aload(ps + 3);
        if (w4 == SENT) w4 = aload(ps + 4);
        if (w5 == SENT) w5 = aload(ps + 5);
        if (w6 == SENT) w6 = aload(ps + 6);
        if (w7 == SENT) w7 = aload(ps + 7);
        if (w0 != SENT && w1 != SENT && w2 != SENT && w3 != SENT &&
            w4 != SENT && w5 != SENT && w6 != SENT && w7 != SENT) break;
        __builtin_amdgcn_s_sleep(1);
      }
      {
        const int m = qq * 2;
        u64x2 a; a[0] = w0; a[1] = w1;
        u64x2 b; b[0] = w2; b[1] = w3;
        *(u64x2*)((char*)hlds + m * 2048 + (((pk * 2 + 0) ^ m) * 16)) = a;
        *(u64x2*)((char*)hlds + m * 2048 + (((pk * 2 + 1) ^ m) * 16)) = b;
      }
      {
        const int m = qq * 2 + 1;
        u64x2 a; a[0] = w4; a[1] = w5;
        u64x2 b; b[0] = w6; b[1] = w7;
        *(u64x2*)((char*)hlds + m * 2048 + (((pk * 2 + 0) ^ m) * 16)) = a;
        *(u64x2*)((char*)hlds + m * 2048 + (((pk * 2 + 1) ^ m) * 16)) = b;
      }
    }
    __syncthreads();   // S2: hlds ready

    f32x4 acc0, acc1, acc2, acc3;
    {
      union { u64 w; u16 s[4]; } xu; xu.w = xw;
      acc0[0] = bf2f(xu.s[0]); acc0[1] = bf2f(xu.s[1]);
      acc0[2] = bf2f(xu.s[2]); acc0[3] = bf2f(xu.s[3]);
    }
    acc1 = (f32x4){0.f,0.f,0.f,0.f};
    acc2 = (f32x4){0.f,0.f,0.f,0.f};
    acc3 = (f32x4){0.f,0.f,0.f,0.f};

    if (t > 0) {
#pragma unroll
      for (int kk = 0; kk < 32; kk++) {
        const int c0 = kk * 4 + (lg >> 1);
        const int sub = (lg & 1) * 4;
        Frag aw, bh;
        aw.h[0] = *(const short4v*)(wl + ((c0 ^ swb) << 3) + sub);
        aw.h[1] = *(const short4v*)(wl + (((c0 + 2) ^ swb) << 3) + sub);
        bh.h[0] = *(const short4v*)(hl + ((c0 ^ swa) << 3) + sub);
        bh.h[1] = *(const short4v*)(hl + (((c0 + 2) ^ swa) << 3) + sub);
        if ((kk & 3) == 0)      acc0 = __builtin_amdgcn_mfma_f32_16x16x32_bf16(aw.v, bh.v, acc0, 0, 0, 0);
        else if ((kk & 3) == 1) acc1 = __builtin_amdgcn_mfma_f32_16x16x32_bf16(aw.v, bh.v, acc1, 0, 0, 0);
        else if ((kk & 3) == 2) acc2 = __builtin_amdgcn_mfma_f32_16x16x32_bf16(aw.v, bh.v, acc2, 0, 0, 0);
        else                    acc3 = __builtin_amdgcn_mfma_f32_16x16x32_bf16(aw.v, bh.v, acc3, 0, 0, 0);
      }
    }
    const f32x4 g4 = (acc0 + acc1) + (acc2 + acc3);  // i,f,g,o for (batch lm, unit wid*4+lg)

    const float si = 1.f / (1.f + __expf(-g4[0]));
    const float sf = 1.f / (1.f + __expf(-g4[1]));
    const float so = 1.f / (1.f + __expf(-g4[3]));
    const float cn = sf * c_reg + si * ftanh(g4[2]);
    c_reg = cn;
    const float hn = so * ftanh(cn);
    const int hb = (int)f2b(hn);

    // gather units wid*4+0..3 of batch lm from lanes lm, lm+16, lm+32, lm+48
    const int v0 = __shfl(hb, lm, 64);
    const int v1 = __shfl(hb, lm + 16, 64);
    const int v2 = __shfl(hb, lm + 32, 64);
    const int v3 = __shfl(hb, lm + 48, 64);
    if (lg == 0 && lm < 8) {
      const u64 pack = (u64)(v0 & 0xFFFF) | ((u64)(v1 & 0xFFFF) << 16)
                     | ((u64)(v2 & 0xFFFF) << 32) | ((u64)(v3 & 0xFFFF) << 48);
      astore((u64*)(hbuf + ((size_t)t * 64 + bx) * 128 + lm * 16 + wid * 4), pack);
      // same pack -> cat row (lm*Tdim+t), cols bx*16 + wid*4 (left half)
      *(u64*)(cat + (size_t)(lm * Tdim + t) * 2048 + bx * 16 + wid * 4) = pack;
    }
    __syncthreads();   // S5: hlds reads done before next step's copy overwrites
  }
}

// blocks 0..63: LSTM; 64..191: k-projection GEMM; 192..255: streamers
// (wo/wq/wc fp32->bf16 converts + pattern_mask byte-pack) hidden under the LSTM.
__global__ __launch_bounds__(256) void lstm_plus(
    const u16* __restrict__ xpre, const u16* __restrict__ whh,
    u16* __restrict__ hbuf, u16* __restrict__ cat,
    const u16* __restrict__ encb, const u16* __restrict__ wkb,
    float* __restrict__ klin, const float* __restrict__ bk,
    const float* __restrict__ wo, u16* __restrict__ wob,
    const float* __restrict__ wq, u16* __restrict__ wqb,
    const float* __restrict__ wc, u16* __restrict__ wcb,
    const void* __restrict__ pmask, unsigned char* __restrict__ pmaskb,
    const int* __restrict__ bflag)
{
  __shared__ alignas(16) char smem[147456];
  const int bx = blockIdx.x;
  if (bx < 64) {
    lstm_body(smem, xpre, whh, hbuf, cat, bx);
  } else if (bx < 192) {
    const int idx = bx - 64;               // 16 m-tiles x 8 n-tiles
    gemm_core<float, false, 0, 1>(smem, smem + 8192, smem + 16384, smem + 24576,
        (idx >> 3) * 128, (idx & 7) * 128, 0,
        encb, 1024, 0, wkb, 1024, 0, klin, 1024, 0, bk, nullptr, nullptr, 1024, 1.f);
  } else {
    const int s = bx - 192;                // 0..63
    const int tid = threadIdx.x;
    // wq convert (1024 x 1024)
    for (int r = s; r < 1024; r += 64) {
      const size_t i = (size_t)r * 1024 + tid * 4;
      const float4 v = *(const float4*)(wq + i);
      u16* op = wqb + i;
      op[0] = f2b(v.x); op[1] = f2b(v.y); op[2] = f2b(v.z); op[3] = f2b(v.w);
    }
    // wc convert (1024 x 2048)
    for (int r = s; r < 1024; r += 64) {
#pragma unroll
      for (int hc = 0; hc < 2; hc++) {
        const size_t i = (size_t)r * 2048 + hc * 1024 + tid * 4;
        const float4 v = *(const float4*)(wc + i);
        u16* op = wcb + i;
        op[0] = f2b(v.x); op[1] = f2b(v.y); op[2] = f2b(v.z); op[3] = f2b(v.w);
      }
    }
    if (wob) {
      for (int r = s; r < Vdim; r += 64) {
        const size_t i = (size_t)r * 1024 + tid * 4;
        const float4 v = *(const float4*)(wo + i);
        u16* op = wob + i;
        op[0] = f2b(v.x); op[1] = f2b(v.y); op[2] = f2b(v.z); op[3] = f2b(v.w);
      }
    }
    if (pmaskb) {
      const int bfl = *bflag;
      const size_t total = (size_t)Bdim * Tdim * Vdim;       // 32,768,000
      const size_t nthr = 64 * 256;
      if (bfl == 0) {     // int32 bools -> bytes
        for (size_t i = ((size_t)s * 256 + tid) * 4; i < total; i += nthr * 4) {
          const int4 v = *(const int4*)((const int*)pmask + i);
          uchar4 o;
          o.x = v.x ? 1 : 0; o.y = v.y ? 1 : 0; o.z = v.z ? 1 : 0; o.w = v.w ? 1 : 0;
          *(uchar4*)(pmaskb + i) = o;
        }
      } else {            // already bytes -> copy 16B
        for (size_t i = ((size_t)s * 256 + tid) * 16; i < total; i += nthr * 16) {
          *(int4*)(pmaskb + i) = *(const int4*)((const unsigned char*)pmask + i);
        }
      }
    }
  }
}

// ---------------- fused prep: weight converts + embed + bias + sentinel + bool-detect
__global__ __launch_bounds__(256) void prep_k(
    const float* __restrict__ w_hh, const float* __restrict__ w_ih,
    const float* __restrict__ wk,   const float* __restrict__ enc,
    const int* __restrict__ ids,
    const float* __restrict__ tok,  const float* __restrict__ pos,
    const float* __restrict__ b_ih, const float* __restrict__ b_hh,
    const unsigned char* __restrict__ pmask,
    u16* __restrict__ whhb, u16* __restrict__ wihb, u16* __restrict__ wkb,
    u16* __restrict__ encb, u16* __restrict__ xbf,
    float* __restrict__ biasf, u64* __restrict__ hbuf, int* __restrict__ bflag)
{
  __shared__ int sdet;
  const int b = blockIdx.x, tid = threadIdx.x;
  if (b < 8192) {                        // gate-permuted whh / w_ih rows
    const bool ih = b >= 4096;
    const int r = b & 4095;
    const int p = (r & 3) * Hdim + (r >> 2);
    const float4 v = *(const float4*)((ih ? w_ih : w_hh) + (size_t)p * Hdim + tid * 4);
    u16* op = (ih ? wihb : whhb) + (size_t)r * Hdim + tid * 4;
    op[0] = f2b(v.x); op[1] = f2b(v.y); op[2] = f2b(v.z); op[3] = f2b(v.w);
  } else if (b < 9216) {                 // wk
    const size_t i = (size_t)(b - 8192) * 1024 + tid * 4;
    const float4 v = *(const float4*)(wk + i);
    u16* op = wkb + i;
    op[0] = f2b(v.x); op[1] = f2b(v.y); op[2] = f2b(v.z); op[3] = f2b(v.w);
  } else if (b < 11264) {                // enc
    const size_t i = (size_t)(b - 9216) * 1024 + tid * 4;
    const float4 v = *(const float4*)(enc + i);
    u16* op = encb + i;
    op[0] = f2b(v.x); op[1] = f2b(v.y); op[2] = f2b(v.z); op[3] = f2b(v.w);
  } else if (b < 12288) {                // embed
    const int row = b - 11264;
    const int t = row & (Tdim - 1);
    const int id = ids[row];
    const int h0 = tid * 4;
    const float4 a = *(const float4*)(tok + (size_t)id * Hdim + h0);
    const float4 p = *(const float4*)(pos + (size_t)t * Hdim + h0);
    u16* op = xbf + (size_t)row * Hdim + h0;
    op[0] = f2b(a.x + p.x); op[1] = f2b(a.y + p.y); op[2] = f2b(a.z + p.z); op[3] = f2b(a.w + p.w);
  } else if (b < 12292) {                // bias fold (gate-permuted)
    const int n0 = (b - 12288) * 1024 + tid * 4;
#pragma unroll
    for (int j = 0; j < 4; j++) {
      const int n = n0 + j;
      const int p = (n & 3) * Hdim + (n >> 2);
      biasf[n] = b_ih[p] + b_hh[p];
    }
  } else if (b < 12548) {                // hbuf sentinel: 256 blocks x 256 thr x 4 u64
    const size_t i = ((size_t)(b - 12292) * 256 + tid) * 4;
    u64x2 s2; s2[0] = SENT; s2[1] = SENT;
    *(u64x2*)(hbuf + i)     = s2;
    *(u64x2*)(hbuf + i + 2) = s2;
  } else {                               // bool dtype detect (1 block)
    if (tid == 0) sdet = 0;
    __syncthreads();
    int loc = 0;
    for (int i = tid; i < 65536; i += 256)
      if ((i & 3) && pmask[i]) loc = 1;
    if (loc) atomicOr(&sdet, 1);
    __syncthreads();
    if (tid == 0) bflag[0] = sdet;
  }
}

// ---------------- small kernels
__global__ __launch_bounds__(256) void ln_rows(const float* __restrict__ in, u16* __restrict__ out,
                                               const float* __restrict__ g, const float* __restrict__ be){
  const int row = blockIdx.x, tid = threadIdx.x;
  const int lane = tid & 63, wid = tid >> 6;
  const float4 x = *(const float4*)(in + (size_t)row * Hdim + tid * 4);
  float s = x.x + x.y + x.z + x.w;
  float q = x.x * x.x + x.y * x.y + x.z * x.z + x.w * x.w;
  for (int o = 32; o; o >>= 1) { s += __shfl_down(s, o, 64); q += __shfl_down(q, o, 64); }
  __shared__ float sm[8];
  if (lane == 0) { sm[wid] = s; sm[4 + wid] = q; }
  __syncthreads();
  const float ts = sm[0] + sm[1] + sm[2] + sm[3];
  const float tq = sm[4] + sm[5] + sm[6] + sm[7];
  const float mean = ts * (1.f / Hdim);
  const float var  = tq * (1.f / Hdim) - mean * mean;
  const float r = rsqrtf(var + 1e-5f);
  const int h0 = tid * 4;
  const float4 gv = *(const float4*)(g + h0);
  const float4 bv = *(const float4*)(be + h0);
  u16* op = out + (size_t)row * Hdim + h0;
  op[0] = f2b((x.x - mean) * r * gv.x + bv.x);
  op[1] = f2b((x.y - mean) * r * gv.y + bv.y);
  op[2] = f2b((x.z - mean) * r * gv.z + bv.z);
  op[3] = f2b((x.w - mean) * r * gv.w + bv.w);
}
__global__ __launch_bounds__(256) void softmax_k(const float* __restrict__ sc, const void* __restrict__ am,
                                                 const int* __restrict__ mflag, u16* __restrict__ w){
  const int row = blockIdx.x, tid = threadIdx.x;
  const int lane = tid & 63, wid = tid >> 6;
  const int b = row >> 7;
  const int bflag = *mflag;
  const float v = sc[(size_t)row * Sdim + tid];
  const bool mk = mask_at(am, (size_t)b * Sdim + tid, bflag);
  const float vm = mk ? v : -10000.0f;
  float mx = vm;
  for (int o = 32; o; o >>= 1) mx = fmaxf(mx, __shfl_down(mx, o, 64));
  __shared__ float sm[8];
  if (lane == 0) sm[wid] = mx;
  __syncthreads();
  mx = fmaxf(fmaxf(sm[0], sm[1]), fmaxf(sm[2], sm[3]));
  const float ex = mk ? expf(vm - mx) : 0.f;
  float ss = ex;
  for (int o = 32; o; o >>= 1) ss += __shfl_down(ss, o, 64);
  if (lane == 0) sm[4 + wid] = ss;
  __syncthreads();
  const float tot = sm[4] + sm[5] + sm[6] + sm[7];
  w[(size_t)row * Sdim + tid] = f2b(ex / (tot + 1e-6f));
}
__global__ __launch_bounds__(256) void transp_k(const u16* __restrict__ kn, u16* __restrict__ knT){
  __shared__ u16 tile[64][65];
  const int b = blockIdx.z, h0 = blockIdx.x * 64, s0 = blockIdx.y * 64;
  const u16* src = kn  + (size_t)b * Sdim * Hdim;
  u16* dst       = knT + (size_t)b * Hdim * Sdim;
  for (int e = threadIdx.x; e < 4096; e += 256) {
    const int r = e >> 6, c = e & 63;
    tile[r][c] = src[(size_t)(s0 + r) * Hdim + h0 + c];
  }
  __syncthreads();
  for (int e = threadIdx.x; e < 4096; e += 256) {
    const int hr = e >> 6, scc = e & 63;
    dst[(size_t)(h0 + hr) * Sdim + s0 + scc] = tile[scc][hr];
  }
}

extern "C" void kernel_launch(void* const* d_in, const int* in_sizes, int n_in,
                              void* d_out, int out_size, void* d_ws, size_t ws_size,
                              hipStream_t stream) {
  const int*   input_ids = (const int*)d_in[0];
  const float* enc   = (const float*)d_in[1];
  const void*  pmask = d_in[2];
  const void*  amask = d_in[3];
  const float* tok  = (const float*)d_in[4];
  const float* pos  = (const float*)d_in[5];
  const float* w_ih = (const float*)d_in[6];
  const float* w_hh = (const float*)d_in[7];
  const float* b_ih = (const float*)d_in[8];
  const float* b_hh = (const float*)d_in[9];
  const float* wq = (const float*)d_in[10];
  const float* bq = (const float*)d_in[11];
  const float* wk = (const float*)d_in[12];
  const float* bk = (const float*)d_in[13];
  const float* wc = (const float*)d_in[14];
  const float* bc = (const float*)d_in[15];
  const float* wo = (const float*)d_in[16];
  const float* bo = (const float*)d_in[17];
  const float* g1  = (const float*)d_in[18];
  const float* be1 = (const float*)d_in[19];
  const float* g2  = (const float*)d_in[20];
  const float* be2 = (const float*)d_in[21];
  float* out = (float*)d_out;

  char* ws = (char*)d_ws;
  size_t off = 0;
  auto alloc = [&](size_t b){ size_t o = off; off += (b + 255) & ~(size_t)255; return o; };
  u16*   whhb  = (u16*)  (ws + alloc((size_t)4096 * 1024 * 2));
  u16*   wihb  = (u16*)  (ws + alloc((size_t)4096 * 1024 * 2));
  u16*   wqb   = (u16*)  (ws + alloc((size_t)1024 * 1024 * 2));
  u16*   wkb   = (u16*)  (ws + alloc((size_t)1024 * 1024 * 2));
  u16*   wcb   = (u16*)  (ws + alloc((size_t)1024 * 2048 * 2));
  float* biasf = (float*)(ws + alloc(4096 * 4));
  u16*   xbf   = (u16*)  (ws + alloc((size_t)1024 * 1024 * 2));
  u16*   encb  = (u16*)  (ws + alloc((size_t)2048 * 1024 * 2));
  u16*   xpre  = (u16*)  (ws + alloc((size_t)1024 * 4096 * 2));
  u16*   hbuf  = (u16*)  (ws + alloc((size_t)Tdim * 64 * 128 * 2));
  u16*   cat   = (u16*)  (ws + alloc((size_t)1024 * 2048 * 2));
  float* qlin  = (float*)(ws + alloc((size_t)1024 * 1024 * 4));
  u16*   qn    = (u16*)  (ws + alloc((size_t)1024 * 1024 * 2));
  float* klin  = (float*)(ws + alloc((size_t)2048 * 1024 * 4));
  u16*   kn    = (u16*)  (ws + alloc((size_t)2048 * 1024 * 2));
  u16*   knT   = (u16*)  (ws + alloc((size_t)2048 * 1024 * 2));
  float* scores= (float*)(ws + alloc((size_t)8 * 128 * 256 * 4));
  u16*   attw  = (u16*)  (ws + alloc((size_t)8 * 128 * 256 * 2));
  float* hlin  = (float*)(ws + alloc((size_t)1024 * 1024 * 4));
  u16*   hid   = (u16*)  (ws + alloc((size_t)1024 * 1024 * 2));
  int*   bflag = (int*)  (ws + alloc(256));
  unsigned char* pmaskb = (unsigned char*)(ws + alloc((size_t)Bdim * Tdim * Vdim));
  const bool havePak = off <= ws_size;
  u16*   wob   = (u16*)  (ws + alloc((size_t)Vdim * Hdim * 2));
  const bool haveWob = off <= ws_size;
  if (!havePak) pmaskb = nullptr;
  if (!haveWob) wob = nullptr;
  (void)in_sizes; (void)n_in; (void)out_size;

  prep_k<<<12549, 256, 0, stream>>>(w_hh, w_ih, wk, enc, input_ids,
      tok, pos, b_ih, b_hh, (const unsigned char*)pmask,
      whhb, wihb, wkb, encb, xbf, biasf, (u64*)hbuf, bflag);

  // x_pre = x @ w_ih_perm.T + (b_ih + b_hh)   -> bf16 (1024 x 4096)
  gemm_bt<u16, false, 0, false><<<dim3(32, 8, 1), 256, 0, stream>>>(
      xbf, 1024, 0, wihb, 1024, 0, xpre, 4096, 0, biasf, nullptr, nullptr, 1024, 1.f);

  // LSTM (0-63, writes hbuf + cat) + k-projection (64-191) + streamers (192-255)
  lstm_plus<<<256, 256, 0, stream>>>(xpre, whhb, hbuf, cat, encb, wkb, klin, bk,
                                     wo, wob, wq, wqb, wc, wcb, pmask, pmaskb, bflag);

  // q = lstm_out @ wq.T + bq ; LN(g1,be1)
  gemm_bt<float, false, 0, false><<<dim3(8, 8, 1), 256, 0, stream>>>(
      cat, 2048, 0, wqb, 1024, 0, qlin, 1024, 0, bq, nullptr, nullptr, 1024, 1.f);
  ln_rows<<<1024, 256, 0, stream>>>(qlin, qn, g1, be1);
  ln_rows<<<2048, 256, 0, stream>>>(klin, kn, g1, be1);
  transp_k<<<dim3(16, 4, 8), 256, 0, stream>>>(kn, knT);

  // scores = qn @ kn^T * scale   (batched over 8)
  gemm_bt<float, false, 0, false><<<dim3(2, 1, 8), 256, 0, stream>>>(
      qn, 1024, 131072, kn, 1024, 262144, scores, 256, 32768, nullptr, nullptr, nullptr, 1024, 0.015625f);
  softmax_k<<<1024, 256, 0, stream>>>(scores, amask, bflag, attw);
  // ctx = w @ kn  -> right half of cat   (batched)
  gemm_bt<u16, false, 0, false><<<dim3(8, 1, 8), 256, 0, stream>>>(
      attw, 256, 32768, knT, 256, 262144, cat + 1024, 2048, 262144, nullptr, nullptr, nullptr, 256, 1.f);

  // hidden = LN( cat @ wc.T + bc ; g2,be2 )
  gemm_bt<float, false, 0, false><<<dim3(8, 8, 1), 256, 0, stream>>>(
      cat, 2048, 0, wcb, 2048, 0, hlin, 1024, 0, bc, nullptr, nullptr, 2048, 1.f);
  ln_rows<<<1024, 256, 0, stream>>>(hlin, hid, g2, be2);

  // logits = hidden @ wo.T + bo, masked — SWAP grid, NT=1 (NT=2 regressed r10)
  if (wob && pmaskb)
    gemm_bt<float, false, 2, true><<<dim3(8, 250, 1), 256, 0, stream>>>(
        hid, 1024, 0, wob, 1024, 0, out, 32000, 0, bo, pmaskb, nullptr, 1024, 1.f);
  else if (wob)
    gemm_bt<float, false, 1, true><<<dim3(8, 250, 1), 256, 0, stream>>>(
        hid, 1024, 0, wob, 1024, 0, out, 32000, 0, bo, pmask, bflag, 1024, 1.f);
  else
    gemm_bt<float, true, 1, true><<<dim3(8, 250, 1), 256, 0, stream>>>(
        hid, 1024, 0, wo, 1024, 0, out, 32000, 0, bo, pmask, bflag, 1024, 1.f);
}

// Round 12
// 793.728 us; speedup vs baseline: 1.0619x; 1.0087x over previous
//
#include <hip/hip_runtime.h>
#include <cstdint>
#include <cstddef>

#define Bdim 8
#define Tdim 128
#define Sdim 256
#define Hdim 1024
#define Vdim 32000
#define SENT 0xFFFFFFFFFFFFFFFFULL

typedef unsigned short u16;
typedef unsigned long long u64;
typedef __attribute__((ext_vector_type(8))) short short8;
typedef __attribute__((ext_vector_type(4))) short short4v;
typedef __attribute__((ext_vector_type(4))) float f32x4;
typedef __attribute__((ext_vector_type(2))) unsigned long long u64x2;

union Frag { short8 v; short4v h[2]; };

__device__ __forceinline__ float bf2f(u16 u){
  union { unsigned int i; float f; } x; x.i = ((unsigned int)u) << 16; return x.f;
}
__device__ __forceinline__ u16 f2b(float f){
  union { float f; unsigned int u; } x; x.f = f;
  unsigned int r = x.u + 0x7FFFu + ((x.u >> 16) & 1u);  // RNE
  return (u16)(r >> 16);
}
__device__ __forceinline__ float ftanh(float x){
  x = fminf(10.f, fmaxf(-10.f, x));
  const float e = __expf(2.f * x);
  return (e - 1.f) / (e + 1.f);
}

__device__ __forceinline__ void gload16(const void* g, void* l){
  __builtin_amdgcn_global_load_lds((const __attribute__((address_space(1))) unsigned int*)g,
                                   (__attribute__((address_space(3))) unsigned int*)l, 16, 0, 0);
}

// 16B-cell swizzle for 64B-wide LDS tile rows (4 cells/row)
__device__ __forceinline__ int qsw(int r){ return (r + (r >> 2)) & 3; }

__device__ __forceinline__ u64 aload(const u64* p){
  return __hip_atomic_load(p, __ATOMIC_RELAXED, __HIP_MEMORY_SCOPE_AGENT);
}
__device__ __forceinline__ void astore(u64* p, u64 v){
  __hip_atomic_store(p, v, __ATOMIC_RELAXED, __HIP_MEMORY_SCOPE_AGENT);
}

__device__ __forceinline__ bool mask_at(const void* m, size_t idx, int byteflag){
  if (byteflag) return ((const unsigned char*)m)[idx] != 0;
  return ((const int*)m)[idx] != 0;
}

// ---------------- 2-phase double-buffered GEMM core (128 x 128 tile)
// MASK: 0 none, 1 runtime-dtype mask via mflag, 2 byte mask.
template<typename OutT, bool BF32, int MASK>
__device__ __forceinline__ void gemm_core(
    char* ldsA0, char* ldsB0, char* ldsA1, char* ldsB1,
    int m0, int n0, int z,
    const u16* __restrict__ A, int lda, long sA,
    const void* __restrict__ Bp, int ldb, long sB,
    OutT* __restrict__ C, int ldc, long sC,
    const float* __restrict__ bias,
    const void* __restrict__ mask,
    const int* __restrict__ mflag,
    int K, float alpha)
{
  const int tid  = threadIdx.x;
  const int lane = tid & 63, wid = tid >> 6;
  const int lm = lane & 15, lg = lane >> 4;
  const int wm = wid >> 1, wn = wid & 1;            // 2x2 waves, 64x64 each
  const char* Ab = (const char*)(A + (size_t)z * sA);

  f32x4 acc[4][4];
#pragma unroll
  for (int i = 0; i < 4; i++)
#pragma unroll
    for (int j = 0; j < 4; j++) acc[i][j] = (f32x4){0.f, 0.f, 0.f, 0.f};

  const int brow = tid >> 1, bhalf = tid & 1;       // BF32 staging coords
  const int qb_st = qsw(brow);

  auto stageA = [&](char* dst, int k0){
    const char* ga = Ab + ((size_t)m0 * lda + k0) * 2;
    const int f0 = tid, f1 = tid + 256;
    const int r0 = f0 >> 2, r1 = f1 >> 2;
    gload16(ga + (size_t)r0 * (lda * 2) + ((f0 & 3) ^ qsw(r0)) * 16, dst + (f0 & ~63) * 16);
    gload16(ga + (size_t)r1 * (lda * 2) + ((f1 & 3) ^ qsw(r1)) * 16, dst + (f1 & ~63) * 16);
  };
  auto stageB16 = [&](char* dst, int k0){
    const char* gb = (const char*)((const u16*)Bp + (size_t)z * sB) + ((size_t)n0 * ldb + k0) * 2;
    const int f0 = tid, f1 = tid + 256;
    const int r0 = f0 >> 2, r1 = f1 >> 2;
    gload16(gb + (size_t)r0 * (ldb * 2) + ((f0 & 3) ^ qsw(r0)) * 16, dst + (f0 & ~63) * 16);
    gload16(gb + (size_t)r1 * (ldb * 2) + ((f1 & 3) ^ qsw(r1)) * 16, dst + (f1 & ~63) * 16);
  };

  float4 nv0, nv1, nv2, nv3;                        // BF32 in-flight tile
  auto loadB32 = [&](int k0){
    const float* Bf = (const float*)Bp + (size_t)z * sB;
    const float4* src = (const float4*)(Bf + (size_t)(n0 + brow) * ldb + k0 + bhalf * 16);
    nv0 = src[0]; nv1 = src[1]; nv2 = src[2]; nv3 = src[3];
  };
  auto writeB32 = [&](char* dst){
    union { short8 v; short s[8]; } p0, p1;
    p0.s[0]=(short)f2b(nv0.x); p0.s[1]=(short)f2b(nv0.y); p0.s[2]=(short)f2b(nv0.z); p0.s[3]=(short)f2b(nv0.w);
    p0.s[4]=(short)f2b(nv1.x); p0.s[5]=(short)f2b(nv1.y); p0.s[6]=(short)f2b(nv1.z); p0.s[7]=(short)f2b(nv1.w);
    p1.s[0]=(short)f2b(nv2.x); p1.s[1]=(short)f2b(nv2.y); p1.s[2]=(short)f2b(nv2.z); p1.s[3]=(short)f2b(nv2.w);
    p1.s[4]=(short)f2b(nv3.x); p1.s[5]=(short)f2b(nv3.y); p1.s[6]=(short)f2b(nv3.z); p1.s[7]=(short)f2b(nv3.w);
    char* base = dst + brow * 64;
    *(short8*)(base + (((bhalf * 2 + 0) ^ qb_st) * 16)) = p0.v;
    *(short8*)(base + (((bhalf * 2 + 1) ^ qb_st) * 16)) = p1.v;
  };

  stageA(ldsA0, 0);
  if (BF32) { loadB32(0); writeB32(ldsB0); }
  else stageB16(ldsB0, 0);
  __syncthreads();

  char *cA = ldsA0, *cB = ldsB0, *nA = ldsA1, *nB = ldsB1;
  const int nk = K >> 5;
  for (int i = 0; i < nk; i++) {
    const bool more = (i + 1) < nk;
    if (more) {               // issue next-tile loads before compute (T3/T14)
      stageA(nA, (i + 1) << 5);
      if (BF32) loadB32((i + 1) << 5);
      else stageB16(nB, (i + 1) << 5);
    }
    Frag a[4];
#pragma unroll
    for (int mi = 0; mi < 4; mi++) {
      const int rr = wm * 64 + mi * 16 + lm;
      const int q = qsw(rr);
      const char* p = cA + rr * 64 + (lg & 1) * 8;
      a[mi].h[0] = *(const short4v*)(p + (((lg >> 1) ^ q) * 16));
      a[mi].h[1] = *(const short4v*)(p + ((((lg >> 1) | 2) ^ q) * 16));
    }
#pragma unroll
    for (int ni = 0; ni < 4; ni++) {
      const int rr = wn * 64 + ni * 16 + lm;
      const int q = qsw(rr);
      const char* p = cB + rr * 64 + (lg & 1) * 8;
      Frag b;
      b.h[0] = *(const short4v*)(p + (((lg >> 1) ^ q) * 16));
      b.h[1] = *(const short4v*)(p + ((((lg >> 1) | 2) ^ q) * 16));
#pragma unroll
      for (int mi = 0; mi < 4; mi++)
        acc[mi][ni] = __builtin_amdgcn_mfma_f32_16x16x32_bf16(a[mi].v, b.v, acc[mi][ni], 0, 0, 0);
    }
    if (BF32 && more) writeB32(nB);    // convert-late
    __syncthreads();
    char* t;
    t = cA; cA = nA; nA = t;
    t = cB; cB = nB; nB = t;
  }

  const int bflag = (MASK == 1) ? *mflag : 0;
#pragma unroll
  for (int mi = 0; mi < 4; mi++) {
#pragma unroll
    for (int ni = 0; ni < 4; ni++) {
      const int row = m0 + wm * 64 + mi * 16 + lg * 4;
      const int col = n0 + wn * 64 + ni * 16 + lm;
      const float bb = bias ? bias[col] : 0.f;
#pragma unroll
      for (int j = 0; j < 4; j++) {
        float v = acc[mi][ni][j] * alpha + bb;
        const size_t midx = (size_t)(row + j) * ldc + col;
        if (MASK == 1) { if (!mask_at(mask, midx, bflag)) v = -10000.0f; }
        if (MASK == 2) { if (!((const unsigned char*)mask)[midx]) v = -10000.0f; }
        const size_t o = (size_t)z * sC + midx;
        if constexpr (sizeof(OutT) == 2) C[o] = (OutT)f2b(v); else C[o] = (OutT)v;
      }
    }
  }
}

template<typename OutT, bool BF32, int MASK, bool SWAP>
__global__ __launch_bounds__(256) void gemm_bt(
    const u16* __restrict__ A, int lda, long sA,
    const void* __restrict__ Bp, int ldb, long sB,
    OutT* __restrict__ C, int ldc, long sC,
    const float* __restrict__ bias,
    const void* __restrict__ mask,
    const int* __restrict__ mflag,
    int K, float alpha)
{
  __shared__ alignas(16) char lds[32768];
  const int m0 = (SWAP ? blockIdx.x : blockIdx.y) * 128;
  const int n0 = (SWAP ? blockIdx.y : blockIdx.x) * 128;
  gemm_core<OutT, BF32, MASK>(lds, lds + 8192, lds + 16384, lds + 24576,
      m0, n0, blockIdx.z, A, lda, sA, Bp, ldb, sB, C, ldc, sC,
      bias, mask, mflag, K, alpha);
}

// ---------------- 256x256-tile 2-phase GEMM for the logits (512 thr, 8 waves 2Mx4N)
// bf16 A/B via global_load_lds (swizzled source), byte-mask + bias epilogue.
// Evidence: 256^2 at the 2-barrier structure = 792 TF @4096^3 (learn_hip m112).
__global__ __launch_bounds__(512) void gemm256_mask(
    const u16* __restrict__ A, int lda,
    const u16* __restrict__ Bt, int ldb,
    float* __restrict__ C, int ldc,
    const float* __restrict__ bias,
    const unsigned char* __restrict__ mask,
    int K)
{
  __shared__ alignas(16) char lds[65536];   // A0 16K | B0 16K | A1 16K | B1 16K
  char* ldsA0 = lds;
  char* ldsB0 = lds + 16384;
  char* ldsA1 = lds + 32768;
  char* ldsB1 = lds + 49152;
  const int tid  = threadIdx.x;
  const int lane = tid & 63, wid = tid >> 6;
  const int lm = lane & 15, lg = lane >> 4;
  const int wm = wid >> 2, wn = wid & 3;            // 2x4 waves, 128x64 each
  const int m0 = blockIdx.x * 256, n0 = blockIdx.y * 256;
  const char* Ab = (const char*)A + (size_t)m0 * lda * 2;
  const char* Bb = (const char*)Bt + (size_t)n0 * ldb * 2;

  f32x4 acc[8][4];
#pragma unroll
  for (int i = 0; i < 8; i++)
#pragma unroll
    for (int j = 0; j < 4; j++) acc[i][j] = (f32x4){0.f, 0.f, 0.f, 0.f};

  auto stageT = [&](const char* G, int ld, char* dst, int k0){
    const char* g = G + (size_t)k0 * 2;
    const int f0 = tid, f1 = tid + 512;               // 1024 cells of 16B (256 rows x 4)
    const int r0 = f0 >> 2, r1 = f1 >> 2;
    gload16(g + (size_t)r0 * (ld * 2) + ((f0 & 3) ^ qsw(r0)) * 16, dst + (f0 & ~63) * 16);
    gload16(g + (size_t)r1 * (ld * 2) + ((f1 & 3) ^ qsw(r1)) * 16, dst + (f1 & ~63) * 16);
  };

  stageT(Ab, lda, ldsA0, 0);
  stageT(Bb, ldb, ldsB0, 0);
  __syncthreads();

  char *cA = ldsA0, *cB = ldsB0, *nA = ldsA1, *nB = ldsB1;
  const int nk = K >> 5;
  for (int i = 0; i < nk; i++) {
    const bool more = (i + 1) < nk;
    if (more) {
      stageT(Ab, lda, nA, (i + 1) << 5);
      stageT(Bb, ldb, nB, (i + 1) << 5);
    }
    Frag a[8];
#pragma unroll
    for (int mi = 0; mi < 8; mi++) {
      const int rr = wm * 128 + mi * 16 + lm;
      const int q = qsw(rr);
      const char* p = cA + rr * 64 + (lg & 1) * 8;
      a[mi].h[0] = *(const short4v*)(p + (((lg >> 1) ^ q) * 16));
      a[mi].h[1] = *(const short4v*)(p + ((((lg >> 1) | 2) ^ q) * 16));
    }
#pragma unroll
    for (int ni = 0; ni < 4; ni++) {
      const int rr = wn * 64 + ni * 16 + lm;
      const int q = qsw(rr);
      const char* p = cB + rr * 64 + (lg & 1) * 8;
      Frag b;
      b.h[0] = *(const short4v*)(p + (((lg >> 1) ^ q) * 16));
      b.h[1] = *(const short4v*)(p + ((((lg >> 1) | 2) ^ q) * 16));
#pragma unroll
      for (int mi = 0; mi < 8; mi++)
        acc[mi][ni] = __builtin_amdgcn_mfma_f32_16x16x32_bf16(a[mi].v, b.v, acc[mi][ni], 0, 0, 0);
    }
    __syncthreads();
    char* t;
    t = cA; cA = nA; nA = t;
    t = cB; cB = nB; nB = t;
  }

#pragma unroll
  for (int mi = 0; mi < 8; mi++) {
#pragma unroll
    for (int ni = 0; ni < 4; ni++) {
      const int row = m0 + wm * 128 + mi * 16 + lg * 4;
      const int col = n0 + wn * 64 + ni * 16 + lm;
      const float bb = bias[col];
#pragma unroll
      for (int j = 0; j < 4; j++) {
        float v = acc[mi][ni][j] + bb;
        const size_t midx = (size_t)(row + j) * ldc + col;
        if (!mask[midx]) v = -10000.0f;
        C[midx] = v;
      }
    }
  }
}

// ---------------- persistent LSTM body: value-polled sync, swapped-operand MFMA
__device__ void lstm_body(char* smem,
    const u16* __restrict__ xpre, const u16* __restrict__ whh,
    u16* __restrict__ hbuf, u16* __restrict__ cat, int bx)
{
  u16* wlds = (u16*)smem;                       // 64x1024, cell c^(r&7) swizzle
  u16* hlds = (u16*)(smem + 131072);            // 8x1024,  cell c^m swizzle
  const int tid = threadIdx.x, lane = tid & 63, wid = tid >> 6;
  const int lm = lane & 15, lg = lane >> 4;
  const int gcol0 = bx * 64;

  for (int q = tid; q < 8192; q += 256) {
    const int r = q >> 7, cc = q & 127;
    gload16(whh + (size_t)(gcol0 + r) * 1024 + (size_t)(cc ^ (r & 7)) * 8,
            (char*)wlds + (q & ~63) * 16);
  }

  float c_reg = 0.f;
  const int rloc = wid * 16 + lm, swb = rloc & 7, swa = lm & 7;
  const u16* wl = wlds + rloc * 1024;
  const u16* hl = hlds + swa * 1024;
  const int pk = tid >> 2, qq = tid & 3;            // consumer: packet, quarter
  const u16* xp = xpre + (size_t)(lm * Tdim) * 4096 + gcol0 + wid * 16 + lg * 4;

  for (int t = 0; t < Tdim; t++) {
    u64 xw = 0;
    if (lm < 8) xw = *(const u64*)(xp + (size_t)t * 4096);
    if (t > 0) {
      const u64* ps = (const u64*)(hbuf + ((size_t)(t - 1) * 64 + pk) * 128) + qq * 8;
      u64 w0=SENT,w1=SENT,w2=SENT,w3=SENT,w4=SENT,w5=SENT,w6=SENT,w7=SENT;
      for (;;) {
        if (w0 == SENT) w0 = aload(ps + 0);
        if (w1 == SENT) w1 = aload(ps + 1);
        if (w2 == SENT) w2 = aload(ps + 2);
        if (w3 == SENT) w3 = aload(ps + 3);
        if (w4 == SENT) w4 = aload(ps + 4);
        if (w5 == SENT) w5 = aload(ps + 5);
        if (w6 == SENT) w6 = aload(ps + 6);
        if (w7 == SENT) w7 = aload(ps + 7);
        if (w0 != SENT && w1 != SENT && w2 != SENT && w3 != SENT &&
            w4 != SENT && w5 != SENT && w6 != SENT && w7 != SENT) break;
        __builtin_amdgcn_s_sleep(1);
      }
      {
        const int m = qq * 2;
        u64x2 a; a[0] = w0; a[1] = w1;
        u64x2 b; b[0] = w2; b[1] = w3;
        *(u64x2*)((char*)hlds + m * 2048 + (((pk * 2 + 0) ^ m) * 16)) = a;
        *(u64x2*)((char*)hlds + m * 2048 + (((pk * 2 + 1) ^ m) * 16)) = b;
      }
      {
        const int m = qq * 2 + 1;
        u64x2 a; a[0] = w4; a[1] = w5;
        u64x2 b; b[0] = w6; b[1] = w7;
        *(u64x2*)((char*)hlds + m * 2048 + (((pk * 2 + 0) ^ m) * 16)) = a;
        *(u64x2*)((char*)hlds + m * 2048 + (((pk * 2 + 1) ^ m) * 16)) = b;
      }
    }
    __syncthreads();   // S2: hlds ready

    f32x4 acc0, acc1, acc2, acc3;
    {
      union { u64 w; u16 s[4]; } xu; xu.w = xw;
      acc0[0] = bf2f(xu.s[0]); acc0[1] = bf2f(xu.s[1]);
      acc0[2] = bf2f(xu.s[2]); acc0[3] = bf2f(xu.s[3]);
    }
    acc1 = (f32x4){0.f,0.f,0.f,0.f};
    acc2 = (f32x4){0.f,0.f,0.f,0.f};
    acc3 = (f32x4){0.f,0.f,0.f,0.f};

    if (t > 0) {
#pragma unroll
      for (int kk = 0; kk < 32; kk++) {
        const int c0 = kk * 4 + (lg >> 1);
        const int sub = (lg & 1) * 4;
        Frag aw, bh;
        aw.h[0] = *(const short4v*)(wl + ((c0 ^ swb) << 3) + sub);
        aw.h[1] = *(const short4v*)(wl + (((c0 + 2) ^ swb) << 3) + sub);
        bh.h[0] = *(const short4v*)(hl + ((c0 ^ swa) << 3) + sub);
        bh.h[1] = *(const short4v*)(hl + (((c0 + 2) ^ swa) << 3) + sub);
        if ((kk & 3) == 0)      acc0 = __builtin_amdgcn_mfma_f32_16x16x32_bf16(aw.v, bh.v, acc0, 0, 0, 0);
        else if ((kk & 3) == 1) acc1 = __builtin_amdgcn_mfma_f32_16x16x32_bf16(aw.v, bh.v, acc1, 0, 0, 0);
        else if ((kk & 3) == 2) acc2 = __builtin_amdgcn_mfma_f32_16x16x32_bf16(aw.v, bh.v, acc2, 0, 0, 0);
        else                    acc3 = __builtin_amdgcn_mfma_f32_16x16x32_bf16(aw.v, bh.v, acc3, 0, 0, 0);
      }
    }
    const f32x4 g4 = (acc0 + acc1) + (acc2 + acc3);  // i,f,g,o for (batch lm, unit wid*4+lg)

    const float si = 1.f / (1.f + __expf(-g4[0]));
    const float sf = 1.f / (1.f + __expf(-g4[1]));
    const float so = 1.f / (1.f + __expf(-g4[3]));
    const float cn = sf * c_reg + si * ftanh(g4[2]);
    c_reg = cn;
    const float hn = so * ftanh(cn);
    const int hb = (int)f2b(hn);

    const int v0 = __shfl(hb, lm, 64);
    const int v1 = __shfl(hb, lm + 16, 64);
    const int v2 = __shfl(hb, lm + 32, 64);
    const int v3 = __shfl(hb, lm + 48, 64);
    if (lg == 0 && lm < 8) {
      const u64 pack = (u64)(v0 & 0xFFFF) | ((u64)(v1 & 0xFFFF) << 16)
                     | ((u64)(v2 & 0xFFFF) << 32) | ((u64)(v3 & 0xFFFF) << 48);
      astore((u64*)(hbuf + ((size_t)t * 64 + bx) * 128 + lm * 16 + wid * 4), pack);
      *(u64*)(cat + (size_t)(lm * Tdim + t) * 2048 + bx * 16 + wid * 4) = pack;
    }
    __syncthreads();   // S5: hlds reads done before next step's copy overwrites
  }
}

// blocks 0..63: LSTM; 64..191: k-projection GEMM; 192..255: streamers
__global__ __launch_bounds__(256) void lstm_plus(
    const u16* __restrict__ xpre, const u16* __restrict__ whh,
    u16* __restrict__ hbuf, u16* __restrict__ cat,
    const u16* __restrict__ encb, const u16* __restrict__ wkb,
    float* __restrict__ klin, const float* __restrict__ bk,
    const float* __restrict__ wo, u16* __restrict__ wob,
    const float* __restrict__ wq, u16* __restrict__ wqb,
    const float* __restrict__ wc, u16* __restrict__ wcb,
    const void* __restrict__ pmask, unsigned char* __restrict__ pmaskb,
    const int* __restrict__ bflag)
{
  __shared__ alignas(16) char smem[147456];
  const int bx = blockIdx.x;
  if (bx < 64) {
    lstm_body(smem, xpre, whh, hbuf, cat, bx);
  } else if (bx < 192) {
    const int idx = bx - 64;               // 16 m-tiles x 8 n-tiles
    gemm_core<float, false, 0>(smem, smem + 8192, smem + 16384, smem + 24576,
        (idx >> 3) * 128, (idx & 7) * 128, 0,
        encb, 1024, 0, wkb, 1024, 0, klin, 1024, 0, bk, nullptr, nullptr, 1024, 1.f);
  } else {
    const int s = bx - 192;                // 0..63
    const int tid = threadIdx.x;
    for (int r = s; r < 1024; r += 64) {
      const size_t i = (size_t)r * 1024 + tid * 4;
      const float4 v = *(const float4*)(wq + i);
      u16* op = wqb + i;
      op[0] = f2b(v.x); op[1] = f2b(v.y); op[2] = f2b(v.z); op[3] = f2b(v.w);
    }
    for (int r = s; r < 1024; r += 64) {
#pragma unroll
      for (int hc = 0; hc < 2; hc++) {
        const size_t i = (size_t)r * 2048 + hc * 1024 + tid * 4;
        const float4 v = *(const float4*)(wc + i);
        u16* op = wcb + i;
        op[0] = f2b(v.x); op[1] = f2b(v.y); op[2] = f2b(v.z); op[3] = f2b(v.w);
      }
    }
    if (wob) {
      for (int r = s; r < Vdim; r += 64) {
        const size_t i = (size_t)r * 1024 + tid * 4;
        const float4 v = *(const float4*)(wo + i);
        u16* op = wob + i;
        op[0] = f2b(v.x); op[1] = f2b(v.y); op[2] = f2b(v.z); op[3] = f2b(v.w);
      }
    }
    if (pmaskb) {
      const int bfl = *bflag;
      const size_t total = (size_t)Bdim * Tdim * Vdim;       // 32,768,000
      const size_t nthr = 64 * 256;
      if (bfl == 0) {     // int32 bools -> bytes
        for (size_t i = ((size_t)s * 256 + tid) * 4; i < total; i += nthr * 4) {
          const int4 v = *(const int4*)((const int*)pmask + i);
          uchar4 o;
          o.x = v.x ? 1 : 0; o.y = v.y ? 1 : 0; o.z = v.z ? 1 : 0; o.w = v.w ? 1 : 0;
          *(uchar4*)(pmaskb + i) = o;
        }
      } else {            // already bytes -> copy 16B
        for (size_t i = ((size_t)s * 256 + tid) * 16; i < total; i += nthr * 16) {
          *(int4*)(pmaskb + i) = *(const int4*)((const unsigned char*)pmask + i);
        }
      }
    }
  }
}

// ---------------- fused prep: weight converts + embed + bias + sentinel + bool-detect
__global__ __launch_bounds__(256) void prep_k(
    const float* __restrict__ w_hh, const float* __restrict__ w_ih,
    const float* __restrict__ wk,   const float* __restrict__ enc,
    const int* __restrict__ ids,
    const float* __restrict__ tok,  const float* __restrict__ pos,
    const float* __restrict__ b_ih, const float* __restrict__ b_hh,
    const unsigned char* __restrict__ pmask,
    u16* __restrict__ whhb, u16* __restrict__ wihb, u16* __restrict__ wkb,
    u16* __restrict__ encb, u16* __restrict__ xbf,
    float* __restrict__ biasf, u64* __restrict__ hbuf, int* __restrict__ bflag)
{
  __shared__ int sdet;
  const int b = blockIdx.x, tid = threadIdx.x;
  if (b < 8192) {                        // gate-permuted whh / w_ih rows
    const bool ih = b >= 4096;
    const int r = b & 4095;
    const int p = (r & 3) * Hdim + (r >> 2);
    const float4 v = *(const float4*)((ih ? w_ih : w_hh) + (size_t)p * Hdim + tid * 4);
    u16* op = (ih ? wihb : whhb) + (size_t)r * Hdim + tid * 4;
    op[0] = f2b(v.x); op[1] = f2b(v.y); op[2] = f2b(v.z); op[3] = f2b(v.w);
  } else if (b < 9216) {                 // wk
    const size_t i = (size_t)(b - 8192) * 1024 + tid * 4;
    const float4 v = *(const float4*)(wk + i);
    u16* op = wkb + i;
    op[0] = f2b(v.x); op[1] = f2b(v.y); op[2] = f2b(v.z); op[3] = f2b(v.w);
  } else if (b < 11264) {                // enc
    const size_t i = (size_t)(b - 9216) * 1024 + tid * 4;
    const float4 v = *(const float4*)(enc + i);
    u16* op = encb + i;
    op[0] = f2b(v.x); op[1] = f2b(v.y); op[2] = f2b(v.z); op[3] = f2b(v.w);
  } else if (b < 12288) {                // embed
    const int row = b - 11264;
    const int t = row & (Tdim - 1);
    const int id = ids[row];
    const int h0 = tid * 4;
    const float4 a = *(const float4*)(tok + (size_t)id * Hdim + h0);
    const float4 p = *(const float4*)(pos + (size_t)t * Hdim + h0);
    u16* op = xbf + (size_t)row * Hdim + h0;
    op[0] = f2b(a.x + p.x); op[1] = f2b(a.y + p.y); op[2] = f2b(a.z + p.z); op[3] = f2b(a.w + p.w);
  } else if (b < 12292) {                // bias fold (gate-permuted)
    const int n0 = (b - 12288) * 1024 + tid * 4;
#pragma unroll
    for (int j = 0; j < 4; j++) {
      const int n = n0 + j;
      const int p = (n & 3) * Hdim + (n >> 2);
      biasf[n] = b_ih[p] + b_hh[p];
    }
  } else if (b < 12548) {                // hbuf sentinel
    const size_t i = ((size_t)(b - 12292) * 256 + tid) * 4;
    u64x2 s2; s2[0] = SENT; s2[1] = SENT;
    *(u64x2*)(hbuf + i)     = s2;
    *(u64x2*)(hbuf + i + 2) = s2;
  } else {                               // bool dtype detect (1 block)
    if (tid == 0) sdet = 0;
    __syncthreads();
    int loc = 0;
    for (int i = tid; i < 65536; i += 256)
      if ((i & 3) && pmask[i]) loc = 1;
    if (loc) atomicOr(&sdet, 1);
    __syncthreads();
    if (tid == 0) bflag[0] = sdet;
  }
}

// ---------------- small kernels
__device__ __forceinline__ void ln_row_body(const float* __restrict__ in, u16* __restrict__ out,
                                            int row, const float* __restrict__ g,
                                            const float* __restrict__ be){
  const int tid = threadIdx.x;
  const int lane = tid & 63, wid = tid >> 6;
  const float4 x = *(const float4*)(in + (size_t)row * Hdim + tid * 4);
  float s = x.x + x.y + x.z + x.w;
  float q = x.x * x.x + x.y * x.y + x.z * x.z + x.w * x.w;
  for (int o = 32; o; o >>= 1) { s += __shfl_down(s, o, 64); q += __shfl_down(q, o, 64); }
  __shared__ float sm[8];
  if (lane == 0) { sm[wid] = s; sm[4 + wid] = q; }
  __syncthreads();
  const float ts = sm[0] + sm[1] + sm[2] + sm[3];
  const float tq = sm[4] + sm[5] + sm[6] + sm[7];
  const float mean = ts * (1.f / Hdim);
  const float var  = tq * (1.f / Hdim) - mean * mean;
  const float r = rsqrtf(var + 1e-5f);
  const int h0 = tid * 4;
  const float4 gv = *(const float4*)(g + h0);
  const float4 bv = *(const float4*)(be + h0);
  u16* op = out + (size_t)row * Hdim + h0;
  op[0] = f2b((x.x - mean) * r * gv.x + bv.x);
  op[1] = f2b((x.y - mean) * r * gv.y + bv.y);
  op[2] = f2b((x.z - mean) * r * gv.z + bv.z);
  op[3] = f2b((x.w - mean) * r * gv.w + bv.w);
}
__global__ __launch_bounds__(256) void ln_rows(const float* __restrict__ in, u16* __restrict__ out,
                                               const float* __restrict__ g, const float* __restrict__ be){
  ln_row_body(in, out, blockIdx.x, g, be);
}
// rows 0..1023: qlin->qn ; rows 1024..3071: klin->kn (both use g1/be1)
__global__ __launch_bounds__(256) void ln_qk(const float* __restrict__ qlin, u16* __restrict__ qn,
                                             const float* __restrict__ klin, u16* __restrict__ kn,
                                             const float* __restrict__ g, const float* __restrict__ be){
  const int row = blockIdx.x;
  if (row < 1024) ln_row_body(qlin, qn, row, g, be);
  else            ln_row_body(klin, kn, row - 1024, g, be);
}
__global__ __launch_bounds__(256) void softmax_k(const float* __restrict__ sc, const void* __restrict__ am,
                                                 const int* __restrict__ mflag, u16* __restrict__ w){
  const int row = blockIdx.x, tid = threadIdx.x;
  const int lane = tid & 63, wid = tid >> 6;
  const int b = row >> 7;
  const int bflag = *mflag;
  const float v = sc[(size_t)row * Sdim + tid];
  const bool mk = mask_at(am, (size_t)b * Sdim + tid, bflag);
  const float vm = mk ? v : -10000.0f;
  float mx = vm;
  for (int o = 32; o; o >>= 1) mx = fmaxf(mx, __shfl_down(mx, o, 64));
  __shared__ float sm[8];
  if (lane == 0) sm[wid] = mx;
  __syncthreads();
  mx = fmaxf(fmaxf(sm[0], sm[1]), fmaxf(sm[2], sm[3]));
  const float ex = mk ? expf(vm - mx) : 0.f;
  float ss = ex;
  for (int o = 32; o; o >>= 1) ss += __shfl_down(ss, o, 64);
  if (lane == 0) sm[4 + wid] = ss;
  __syncthreads();
  const float tot = sm[4] + sm[5] + sm[6] + sm[7];
  w[(size_t)row * Sdim + tid] = f2b(ex / (tot + 1e-6f));
}
__global__ __launch_bounds__(256) void transp_k(const u16* __restrict__ kn, u16* __restrict__ knT){
  __shared__ u16 tile[64][65];
  const int b = blockIdx.z, h0 = blockIdx.x * 64, s0 = blockIdx.y * 64;
  const u16* src = kn  + (size_t)b * Sdim * Hdim;
  u16* dst       = knT + (size_t)b * Hdim * Sdim;
  for (int e = threadIdx.x; e < 4096; e += 256) {
    const int r = e >> 6, c = e & 63;
    tile[r][c] = src[(size_t)(s0 + r) * Hdim + h0 + c];
  }
  __syncthreads();
  for (int e = threadIdx.x; e < 4096; e += 256) {
    const int hr = e >> 6, scc = e & 63;
    dst[(size_t)(h0 + hr) * Sdim + s0 + scc] = tile[scc][hr];
  }
}

extern "C" void kernel_launch(void* const* d_in, const int* in_sizes, int n_in,
                              void* d_out, int out_size, void* d_ws, size_t ws_size,
                              hipStream_t stream) {
  const int*   input_ids = (const int*)d_in[0];
  const float* enc   = (const float*)d_in[1];
  const void*  pmask = d_in[2];
  const void*  amask = d_in[3];
  const float* tok  = (const float*)d_in[4];
  const float* pos  = (const float*)d_in[5];
  const float* w_ih = (const float*)d_in[6];
  const float* w_hh = (const float*)d_in[7];
  const float* b_ih = (const float*)d_in[8];
  const float* b_hh = (const float*)d_in[9];
  const float* wq = (const float*)d_in[10];
  const float* bq = (const float*)d_in[11];
  const float* wk = (const float*)d_in[12];
  const float* bk = (const float*)d_in[13];
  const float* wc = (const float*)d_in[14];
  const float* bc = (const float*)d_in[15];
  const float* wo = (const float*)d_in[16];
  const float* bo = (const float*)d_in[17];
  const float* g1  = (const float*)d_in[18];
  const float* be1 = (const float*)d_in[19];
  const float* g2  = (const float*)d_in[20];
  const float* be2 = (const float*)d_in[21];
  float* out = (float*)d_out;

  char* ws = (char*)d_ws;
  size_t off = 0;
  auto alloc = [&](size_t b){ size_t o = off; off += (b + 255) & ~(size_t)255; return o; };
  u16*   whhb  = (u16*)  (ws + alloc((size_t)4096 * 1024 * 2));
  u16*   wihb  = (u16*)  (ws + alloc((size_t)4096 * 1024 * 2));
  u16*   wqb   = (u16*)  (ws + alloc((size_t)1024 * 1024 * 2));
  u16*   wkb   = (u16*)  (ws + alloc((size_t)1024 * 1024 * 2));
  u16*   wcb   = (u16*)  (ws + alloc((size_t)1024 * 2048 * 2));
  float* biasf = (float*)(ws + alloc(4096 * 4));
  u16*   xbf   = (u16*)  (ws + alloc((size_t)1024 * 1024 * 2));
  u16*   encb  = (u16*)  (ws + alloc((size_t)2048 * 1024 * 2));
  u16*   xpre  = (u16*)  (ws + alloc((size_t)1024 * 4096 * 2));
  u16*   hbuf  = (u16*)  (ws + alloc((size_t)Tdim * 64 * 128 * 2));
  u16*   cat   = (u16*)  (ws + alloc((size_t)1024 * 2048 * 2));
  float* qlin  = (float*)(ws + alloc((size_t)1024 * 1024 * 4));
  u16*   qn    = (u16*)  (ws + alloc((size_t)1024 * 1024 * 2));
  float* klin  = (float*)(ws + alloc((size_t)2048 * 1024 * 4));
  u16*   kn    = (u16*)  (ws + alloc((size_t)2048 * 1024 * 2));
  u16*   knT   = (u16*)  (ws + alloc((size_t)2048 * 1024 * 2));
  float* scores= (float*)(ws + alloc((size_t)8 * 128 * 256 * 4));
  u16*   attw  = (u16*)  (ws + alloc((size_t)8 * 128 * 256 * 2));
  float* hlin  = (float*)(ws + alloc((size_t)1024 * 1024 * 4));
  u16*   hid   = (u16*)  (ws + alloc((size_t)1024 * 1024 * 2));
  int*   bflag = (int*)  (ws + alloc(256));
  unsigned char* pmaskb = (unsigned char*)(ws + alloc((size_t)Bdim * Tdim * Vdim));
  const bool havePak = off <= ws_size;
  u16*   wob   = (u16*)  (ws + alloc((size_t)Vdim * Hdim * 2));
  const bool haveWob = off <= ws_size;
  if (!havePak) pmaskb = nullptr;
  if (!haveWob) wob = nullptr;
  (void)in_sizes; (void)n_in; (void)out_size;

  prep_k<<<12549, 256, 0, stream>>>(w_hh, w_ih, wk, enc, input_ids,
      tok, pos, b_ih, b_hh, (const unsigned char*)pmask,
      whhb, wihb, wkb, encb, xbf, biasf, (u64*)hbuf, bflag);

  // x_pre = x @ w_ih_perm.T + (b_ih + b_hh)   -> bf16 (1024 x 4096)
  gemm_bt<u16, false, 0, false><<<dim3(32, 8, 1), 256, 0, stream>>>(
      xbf, 1024, 0, wihb, 1024, 0, xpre, 4096, 0, biasf, nullptr, nullptr, 1024, 1.f);

  // LSTM (0-63, writes hbuf + cat) + k-projection (64-191) + streamers (192-255)
  lstm_plus<<<256, 256, 0, stream>>>(xpre, whhb, hbuf, cat, encb, wkb, klin, bk,
                                     wo, wob, wq, wqb, wc, wcb, pmask, pmaskb, bflag);

  // q = lstm_out @ wq.T + bq ; then LN both q and k in one launch
  gemm_bt<float, false, 0, false><<<dim3(8, 8, 1), 256, 0, stream>>>(
      cat, 2048, 0, wqb, 1024, 0, qlin, 1024, 0, bq, nullptr, nullptr, 1024, 1.f);
  ln_qk<<<3072, 256, 0, stream>>>(qlin, qn, klin, kn, g1, be1);
  transp_k<<<dim3(16, 4, 8), 256, 0, stream>>>(kn, knT);

  // scores = qn @ kn^T * scale   (batched over 8)
  gemm_bt<float, false, 0, false><<<dim3(2, 1, 8), 256, 0, stream>>>(
      qn, 1024, 131072, kn, 1024, 262144, scores, 256, 32768, nullptr, nullptr, nullptr, 1024, 0.015625f);
  softmax_k<<<1024, 256, 0, stream>>>(scores, amask, bflag, attw);
  // ctx = w @ kn  -> right half of cat   (batched)
  gemm_bt<u16, false, 0, false><<<dim3(8, 1, 8), 256, 0, stream>>>(
      attw, 256, 32768, knT, 256, 262144, cat + 1024, 2048, 262144, nullptr, nullptr, nullptr, 256, 1.f);

  // hidden = LN( cat @ wc.T + bc ; g2,be2 )
  gemm_bt<float, false, 0, false><<<dim3(8, 8, 1), 256, 0, stream>>>(
      cat, 2048, 0, wcb, 2048, 0, hlin, 1024, 0, bc, nullptr, nullptr, 2048, 1.f);
  ln_rows<<<1024, 256, 0, stream>>>(hlin, hid, g2, be2);

  // logits = hidden @ wo.T + bo, masked — 256^2 tile 2-phase (m112: 792 TF)
  if (wob && pmaskb)
    gemm256_mask<<<dim3(4, 125, 1), 512, 0, stream>>>(
        hid, 1024, wob, 1024, out, 32000, bo, pmaskb, 1024);
  else if (wob)
    gemm_bt<float, false, 1, true><<<dim3(8, 250, 1), 256, 0, stream>>>(
        hid, 1024, 0, wob, 1024, 0, out, 32000, 0, bo, pmask, bflag, 1024, 1.f);
  else
    gemm_bt<float, true, 1, true><<<dim3(8, 250, 1), 256, 0, stream>>>(
        hid, 1024, 0, wo, 1024, 0, out, 32000, 0, bo, pmask, bflag, 1024, 1.f);
}

// Round 13
// 777.785 us; speedup vs baseline: 1.0837x; 1.0205x over previous
//
#include <hip/hip_runtime.h>
#include <cstdint>
#include <cstddef>

#define Bdim 8
#define Tdim 128
#define Sdim 256
#define Hdim 1024
#define Vdim 32000
#define SENT 0xFFFFFFFFFFFFFFFFULL

typedef unsigned short u16;
typedef unsigned long long u64;
typedef __attribute__((ext_vector_type(8))) short short8;
typedef __attribute__((ext_vector_type(4))) short short4v;
typedef __attribute__((ext_vector_type(4))) float f32x4;
typedef __attribute__((ext_vector_type(2))) unsigned long long u64x2;

union Frag { short8 v; short4v h[2]; };

__device__ __forceinline__ float bf2f(u16 u){
  union { unsigned int i; float f; } x; x.i = ((unsigned int)u) << 16; return x.f;
}
__device__ __forceinline__ u16 f2b(float f){
  union { float f; unsigned int u; } x; x.f = f;
  unsigned int r = x.u + 0x7FFFu + ((x.u >> 16) & 1u);  // RNE
  return (u16)(r >> 16);
}
__device__ __forceinline__ float ftanh(float x){
  x = fminf(10.f, fmaxf(-10.f, x));
  const float e = __expf(2.f * x);
  return (e - 1.f) / (e + 1.f);
}

__device__ __forceinline__ void gload16(const void* g, void* l){
  __builtin_amdgcn_global_load_lds((const __attribute__((address_space(1))) unsigned int*)g,
                                   (__attribute__((address_space(3))) unsigned int*)l, 16, 0, 0);
}

// 16B-cell swizzle for 64B-wide LDS tile rows (4 cells/row)
__device__ __forceinline__ int qsw(int r){ return (r + (r >> 2)) & 3; }

__device__ __forceinline__ u64 aload(const u64* p){
  return __hip_atomic_load(p, __ATOMIC_RELAXED, __HIP_MEMORY_SCOPE_AGENT);
}
__device__ __forceinline__ void astore(u64* p, u64 v){
  __hip_atomic_store(p, v, __ATOMIC_RELAXED, __HIP_MEMORY_SCOPE_AGENT);
}

__device__ __forceinline__ bool mask_at(const void* m, size_t idx, int byteflag){
  if (byteflag) return ((const unsigned char*)m)[idx] != 0;
  return ((const int*)m)[idx] != 0;
}

// ---------------- 2-phase double-buffered GEMM core (128 x 128 tile)
// MASK: 0 none, 1 runtime-dtype mask via mflag, 2 byte mask. ATOMIC: atomicAdd C.
template<typename OutT, bool BF32, int MASK, bool ATOMIC = false>
__device__ __forceinline__ void gemm_core(
    char* ldsA0, char* ldsB0, char* ldsA1, char* ldsB1,
    int m0, int n0, int z,
    const u16* __restrict__ A, int lda, long sA,
    const void* __restrict__ Bp, int ldb, long sB,
    OutT* __restrict__ C, int ldc, long sC,
    const float* __restrict__ bias,
    const void* __restrict__ mask,
    const int* __restrict__ mflag,
    int K, float alpha)
{
  const int tid  = threadIdx.x;
  const int lane = tid & 63, wid = tid >> 6;
  const int lm = lane & 15, lg = lane >> 4;
  const int wm = wid >> 1, wn = wid & 1;            // 2x2 waves, 64x64 each
  const char* Ab = (const char*)(A + (size_t)z * sA);

  f32x4 acc[4][4];
#pragma unroll
  for (int i = 0; i < 4; i++)
#pragma unroll
    for (int j = 0; j < 4; j++) acc[i][j] = (f32x4){0.f, 0.f, 0.f, 0.f};

  const int brow = tid >> 1, bhalf = tid & 1;       // BF32 staging coords
  const int qb_st = qsw(brow);

  auto stageA = [&](char* dst, int k0){
    const char* ga = Ab + ((size_t)m0 * lda + k0) * 2;
    const int f0 = tid, f1 = tid + 256;
    const int r0 = f0 >> 2, r1 = f1 >> 2;
    gload16(ga + (size_t)r0 * (lda * 2) + ((f0 & 3) ^ qsw(r0)) * 16, dst + (f0 & ~63) * 16);
    gload16(ga + (size_t)r1 * (lda * 2) + ((f1 & 3) ^ qsw(r1)) * 16, dst + (f1 & ~63) * 16);
  };
  auto stageB16 = [&](char* dst, int k0){
    const char* gb = (const char*)((const u16*)Bp + (size_t)z * sB) + ((size_t)n0 * ldb + k0) * 2;
    const int f0 = tid, f1 = tid + 256;
    const int r0 = f0 >> 2, r1 = f1 >> 2;
    gload16(gb + (size_t)r0 * (ldb * 2) + ((f0 & 3) ^ qsw(r0)) * 16, dst + (f0 & ~63) * 16);
    gload16(gb + (size_t)r1 * (ldb * 2) + ((f1 & 3) ^ qsw(r1)) * 16, dst + (f1 & ~63) * 16);
  };

  float4 nv0, nv1, nv2, nv3;                        // BF32 in-flight tile
  auto loadB32 = [&](int k0){
    const float* Bf = (const float*)Bp + (size_t)z * sB;
    const float4* src = (const float4*)(Bf + (size_t)(n0 + brow) * ldb + k0 + bhalf * 16);
    nv0 = src[0]; nv1 = src[1]; nv2 = src[2]; nv3 = src[3];
  };
  auto writeB32 = [&](char* dst){
    union { short8 v; short s[8]; } p0, p1;
    p0.s[0]=(short)f2b(nv0.x); p0.s[1]=(short)f2b(nv0.y); p0.s[2]=(short)f2b(nv0.z); p0.s[3]=(short)f2b(nv0.w);
    p0.s[4]=(short)f2b(nv1.x); p0.s[5]=(short)f2b(nv1.y); p0.s[6]=(short)f2b(nv1.z); p0.s[7]=(short)f2b(nv1.w);
    p1.s[0]=(short)f2b(nv2.x); p1.s[1]=(short)f2b(nv2.y); p1.s[2]=(short)f2b(nv2.z); p1.s[3]=(short)f2b(nv2.w);
    p1.s[4]=(short)f2b(nv3.x); p1.s[5]=(short)f2b(nv3.y); p1.s[6]=(short)f2b(nv3.z); p1.s[7]=(short)f2b(nv3.w);
    char* base = dst + brow * 64;
    *(short8*)(base + (((bhalf * 2 + 0) ^ qb_st) * 16)) = p0.v;
    *(short8*)(base + (((bhalf * 2 + 1) ^ qb_st) * 16)) = p1.v;
  };

  stageA(ldsA0, 0);
  if (BF32) { loadB32(0); writeB32(ldsB0); }
  else stageB16(ldsB0, 0);
  __syncthreads();

  char *cA = ldsA0, *cB = ldsB0, *nA = ldsA1, *nB = ldsB1;
  const int nk = K >> 5;
  for (int i = 0; i < nk; i++) {
    const bool more = (i + 1) < nk;
    if (more) {               // issue next-tile loads before compute (T3/T14)
      stageA(nA, (i + 1) << 5);
      if (BF32) loadB32((i + 1) << 5);
      else stageB16(nB, (i + 1) << 5);
    }
    Frag a[4];
#pragma unroll
    for (int mi = 0; mi < 4; mi++) {
      const int rr = wm * 64 + mi * 16 + lm;
      const int q = qsw(rr);
      const char* p = cA + rr * 64 + (lg & 1) * 8;
      a[mi].h[0] = *(const short4v*)(p + (((lg >> 1) ^ q) * 16));
      a[mi].h[1] = *(const short4v*)(p + ((((lg >> 1) | 2) ^ q) * 16));
    }
#pragma unroll
    for (int ni = 0; ni < 4; ni++) {
      const int rr = wn * 64 + ni * 16 + lm;
      const int q = qsw(rr);
      const char* p = cB + rr * 64 + (lg & 1) * 8;
      Frag b;
      b.h[0] = *(const short4v*)(p + (((lg >> 1) ^ q) * 16));
      b.h[1] = *(const short4v*)(p + ((((lg >> 1) | 2) ^ q) * 16));
#pragma unroll
      for (int mi = 0; mi < 4; mi++)
        acc[mi][ni] = __builtin_amdgcn_mfma_f32_16x16x32_bf16(a[mi].v, b.v, acc[mi][ni], 0, 0, 0);
    }
    if (BF32 && more) writeB32(nB);    // convert-late
    __syncthreads();
    char* t;
    t = cA; cA = nA; nA = t;
    t = cB; cB = nB; nB = t;
  }

  const int bflag = (MASK == 1) ? *mflag : 0;
#pragma unroll
  for (int mi = 0; mi < 4; mi++) {
#pragma unroll
    for (int ni = 0; ni < 4; ni++) {
      const int row = m0 + wm * 64 + mi * 16 + lg * 4;
      const int col = n0 + wn * 64 + ni * 16 + lm;
      const float bb = bias ? bias[col] : 0.f;
#pragma unroll
      for (int j = 0; j < 4; j++) {
        float v = acc[mi][ni][j] * alpha + bb;
        const size_t midx = (size_t)(row + j) * ldc + col;
        if (MASK == 1) { if (!mask_at(mask, midx, bflag)) v = -10000.0f; }
        if (MASK == 2) { if (!((const unsigned char*)mask)[midx]) v = -10000.0f; }
        const size_t o = (size_t)z * sC + midx;
        if constexpr (ATOMIC) {
          atomicAdd((float*)&C[o], v);
        } else {
          if constexpr (sizeof(OutT) == 2) C[o] = (OutT)f2b(v); else C[o] = (OutT)v;
        }
      }
    }
  }
}

// XSWZ: XCD-bijective remap so the gridDim.x m-blocks sharing a B-tile land on
// ONE XCD (L = (bid%8)*per + bid/8) — kills the 8x wo HBM refetch (T1, r2 evidence).
template<typename OutT, bool BF32, int MASK, bool SWAP, bool XSWZ = false>
__global__ __launch_bounds__(256) void gemm_bt(
    const u16* __restrict__ A, int lda, long sA,
    const void* __restrict__ Bp, int ldb, long sB,
    OutT* __restrict__ C, int ldc, long sC,
    const float* __restrict__ bias,
    const void* __restrict__ mask,
    const int* __restrict__ mflag,
    int K, float alpha)
{
  __shared__ alignas(16) char lds[32768];
  int m0, n0;
  if (XSWZ) {
    const int bid = blockIdx.x + gridDim.x * blockIdx.y;
    const int per = (gridDim.x * gridDim.y) >> 3;      // blocks per XCD (divisible)
    const int L = (bid & 7) * per + (bid >> 3);
    m0 = (L % gridDim.x) * 128;
    n0 = (L / gridDim.x) * 128;
  } else {
    m0 = (SWAP ? blockIdx.x : blockIdx.y) * 128;
    n0 = (SWAP ? blockIdx.y : blockIdx.x) * 128;
  }
  gemm_core<OutT, BF32, MASK>(lds, lds + 8192, lds + 16384, lds + 24576,
      m0, n0, blockIdx.z, A, lda, sA, Bp, ldb, sB, C, ldc, sC,
      bias, mask, mflag, K, alpha);
}

// split-K scores GEMM: grid (n-tiles, k-chunks, batch); atomicAdd into zeroed C.
__global__ __launch_bounds__(256) void gemm_sk(
    const u16* __restrict__ A, int lda, long sA,
    const u16* __restrict__ Bt, int ldb, long sB,
    float* __restrict__ C, int ldc, long sC, float alpha)
{
  __shared__ alignas(16) char lds[32768];
  const int kc = blockIdx.y;
  gemm_core<float, false, 0, true>(lds, lds + 8192, lds + 16384, lds + 24576,
      0, blockIdx.x * 128, blockIdx.z,
      A + kc * 256, lda, sA, Bt + kc * 256, ldb, sB,
      C, ldc, sC, nullptr, nullptr, nullptr, 256, alpha);
}

// ---------------- persistent LSTM body: value-polled sync, swapped-operand MFMA
__device__ void lstm_body(char* smem,
    const u16* __restrict__ xpre, const u16* __restrict__ whh,
    u16* __restrict__ hbuf, u16* __restrict__ cat, int bx)
{
  u16* wlds = (u16*)smem;                       // 64x1024, cell c^(r&7) swizzle
  u16* hlds = (u16*)(smem + 131072);            // 8x1024,  cell c^m swizzle
  const int tid = threadIdx.x, lane = tid & 63, wid = tid >> 6;
  const int lm = lane & 15, lg = lane >> 4;
  const int gcol0 = bx * 64;

  for (int q = tid; q < 8192; q += 256) {
    const int r = q >> 7, cc = q & 127;
    gload16(whh + (size_t)(gcol0 + r) * 1024 + (size_t)(cc ^ (r & 7)) * 8,
            (char*)wlds + (q & ~63) * 16);
  }

  float c_reg = 0.f;
  const int rloc = wid * 16 + lm, swb = rloc & 7, swa = lm & 7;
  const u16* wl = wlds + rloc * 1024;
  const u16* hl = hlds + swa * 1024;
  const int pk = tid >> 2, qq = tid & 3;            // consumer: packet, quarter
  const u16* xp = xpre + (size_t)(lm * Tdim) * 4096 + gcol0 + wid * 16 + lg * 4;

  for (int t = 0; t < Tdim; t++) {
    u64 xw = 0;
    if (lm < 8) xw = *(const u64*)(xp + (size_t)t * 4096);
    if (t > 0) {
      const u64* ps = (const u64*)(hbuf + ((size_t)(t - 1) * 64 + pk) * 128) + qq * 8;
      u64 w0=SENT,w1=SENT,w2=SENT,w3=SENT,w4=SENT,w5=SENT,w6=SENT,w7=SENT;
      for (;;) {
        if (w0 == SENT) w0 = aload(ps + 0);
        if (w1 == SENT) w1 = aload(ps + 1);
        if (w2 == SENT) w2 = aload(ps + 2);
        if (w3 == SENT) w3 = aload(ps + 3);
        if (w4 == SENT) w4 = aload(ps + 4);
        if (w5 == SENT) w5 = aload(ps + 5);
        if (w6 == SENT) w6 = aload(ps + 6);
        if (w7 == SENT) w7 = aload(ps + 7);
        if (w0 != SENT && w1 != SENT && w2 != SENT && w3 != SENT &&
            w4 != SENT && w5 != SENT && w6 != SENT && w7 != SENT) break;
        __builtin_amdgcn_s_sleep(1);
      }
      {
        const int m = qq * 2;
        u64x2 a; a[0] = w0; a[1] = w1;
        u64x2 b; b[0] = w2; b[1] = w3;
        *(u64x2*)((char*)hlds + m * 2048 + (((pk * 2 + 0) ^ m) * 16)) = a;
        *(u64x2*)((char*)hlds + m * 2048 + (((pk * 2 + 1) ^ m) * 16)) = b;
      }
      {
        const int m = qq * 2 + 1;
        u64x2 a; a[0] = w4; a[1] = w5;
        u64x2 b; b[0] = w6; b[1] = w7;
        *(u64x2*)((char*)hlds + m * 2048 + (((pk * 2 + 0) ^ m) * 16)) = a;
        *(u64x2*)((char*)hlds + m * 2048 + (((pk * 2 + 1) ^ m) * 16)) = b;
      }
    }
    __syncthreads();   // S2: hlds ready

    f32x4 acc0, acc1, acc2, acc3;
    {
      union { u64 w; u16 s[4]; } xu; xu.w = xw;
      acc0[0] = bf2f(xu.s[0]); acc0[1] = bf2f(xu.s[1]);
      acc0[2] = bf2f(xu.s[2]); acc0[3] = bf2f(xu.s[3]);
    }
    acc1 = (f32x4){0.f,0.f,0.f,0.f};
    acc2 = (f32x4){0.f,0.f,0.f,0.f};
    acc3 = (f32x4){0.f,0.f,0.f,0.f};

    if (t > 0) {
#pragma unroll
      for (int kk = 0; kk < 32; kk++) {
        const int c0 = kk * 4 + (lg >> 1);
        const int sub = (lg & 1) * 4;
        Frag aw, bh;
        aw.h[0] = *(const short4v*)(wl + ((c0 ^ swb) << 3) + sub);
        aw.h[1] = *(const short4v*)(wl + (((c0 + 2) ^ swb) << 3) + sub);
        bh.h[0] = *(const short4v*)(hl + ((c0 ^ swa) << 3) + sub);
        bh.h[1] = *(const short4v*)(hl + (((c0 + 2) ^ swa) << 3) + sub);
        if ((kk & 3) == 0)      acc0 = __builtin_amdgcn_mfma_f32_16x16x32_bf16(aw.v, bh.v, acc0, 0, 0, 0);
        else if ((kk & 3) == 1) acc1 = __builtin_amdgcn_mfma_f32_16x16x32_bf16(aw.v, bh.v, acc1, 0, 0, 0);
        else if ((kk & 3) == 2) acc2 = __builtin_amdgcn_mfma_f32_16x16x32_bf16(aw.v, bh.v, acc2, 0, 0, 0);
        else                    acc3 = __builtin_amdgcn_mfma_f32_16x16x32_bf16(aw.v, bh.v, acc3, 0, 0, 0);
      }
    }
    const f32x4 g4 = (acc0 + acc1) + (acc2 + acc3);  // i,f,g,o for (batch lm, unit wid*4+lg)

    const float si = 1.f / (1.f + __expf(-g4[0]));
    const float sf = 1.f / (1.f + __expf(-g4[1]));
    const float so = 1.f / (1.f + __expf(-g4[3]));
    const float cn = sf * c_reg + si * ftanh(g4[2]);
    c_reg = cn;
    const float hn = so * ftanh(cn);
    const int hb = (int)f2b(hn);

    const int v0 = __shfl(hb, lm, 64);
    const int v1 = __shfl(hb, lm + 16, 64);
    const int v2 = __shfl(hb, lm + 32, 64);
    const int v3 = __shfl(hb, lm + 48, 64);
    if (lg == 0 && lm < 8) {
      const u64 pack = (u64)(v0 & 0xFFFF) | ((u64)(v1 & 0xFFFF) << 16)
                     | ((u64)(v2 & 0xFFFF) << 32) | ((u64)(v3 & 0xFFFF) << 48);
      astore((u64*)(hbuf + ((size_t)t * 64 + bx) * 128 + lm * 16 + wid * 4), pack);
      *(u64*)(cat + (size_t)(lm * Tdim + t) * 2048 + bx * 16 + wid * 4) = pack;
    }
    __syncthreads();   // S5: hlds reads done before next step's copy overwrites
  }
}

// blocks 0..63: LSTM; 64..191: k-projection GEMM; 192..255: streamers
__global__ __launch_bounds__(256) void lstm_plus(
    const u16* __restrict__ xpre, const u16* __restrict__ whh,
    u16* __restrict__ hbuf, u16* __restrict__ cat,
    const u16* __restrict__ encb, const u16* __restrict__ wkb,
    float* __restrict__ klin, const float* __restrict__ bk,
    const float* __restrict__ wo, u16* __restrict__ wob,
    const float* __restrict__ wq, u16* __restrict__ wqb,
    const float* __restrict__ wc, u16* __restrict__ wcb,
    const void* __restrict__ pmask, unsigned char* __restrict__ pmaskb,
    const int* __restrict__ bflag)
{
  __shared__ alignas(16) char smem[147456];
  const int bx = blockIdx.x;
  if (bx < 64) {
    lstm_body(smem, xpre, whh, hbuf, cat, bx);
  } else if (bx < 192) {
    const int idx = bx - 64;               // 16 m-tiles x 8 n-tiles
    gemm_core<float, false, 0>(smem, smem + 8192, smem + 16384, smem + 24576,
        (idx >> 3) * 128, (idx & 7) * 128, 0,
        encb, 1024, 0, wkb, 1024, 0, klin, 1024, 0, bk, nullptr, nullptr, 1024, 1.f);
  } else {
    const int s = bx - 192;                // 0..63
    const int tid = threadIdx.x;
    for (int r = s; r < 1024; r += 64) {
      const size_t i = (size_t)r * 1024 + tid * 4;
      const float4 v = *(const float4*)(wq + i);
      u16* op = wqb + i;
      op[0] = f2b(v.x); op[1] = f2b(v.y); op[2] = f2b(v.z); op[3] = f2b(v.w);
    }
    for (int r = s; r < 1024; r += 64) {
#pragma unroll
      for (int hc = 0; hc < 2; hc++) {
        const size_t i = (size_t)r * 2048 + hc * 1024 + tid * 4;
        const float4 v = *(const float4*)(wc + i);
        u16* op = wcb + i;
        op[0] = f2b(v.x); op[1] = f2b(v.y); op[2] = f2b(v.z); op[3] = f2b(v.w);
      }
    }
    if (wob) {
      for (int r = s; r < Vdim; r += 64) {
        const size_t i = (size_t)r * 1024 + tid * 4;
        const float4 v = *(const float4*)(wo + i);
        u16* op = wob + i;
        op[0] = f2b(v.x); op[1] = f2b(v.y); op[2] = f2b(v.z); op[3] = f2b(v.w);
      }
    }
    if (pmaskb) {
      const int bfl = *bflag;
      const size_t total = (size_t)Bdim * Tdim * Vdim;       // 32,768,000
      const size_t nthr = 64 * 256;
      if (bfl == 0) {     // int32 bools -> bytes
        for (size_t i = ((size_t)s * 256 + tid) * 4; i < total; i += nthr * 4) {
          const int4 v = *(const int4*)((const int*)pmask + i);
          uchar4 o;
          o.x = v.x ? 1 : 0; o.y = v.y ? 1 : 0; o.z = v.z ? 1 : 0; o.w = v.w ? 1 : 0;
          *(uchar4*)(pmaskb + i) = o;
        }
      } else {            // already bytes -> copy 16B
        for (size_t i = ((size_t)s * 256 + tid) * 16; i < total; i += nthr * 16) {
          *(int4*)(pmaskb + i) = *(const int4*)((const unsigned char*)pmask + i);
        }
      }
    }
  }
}

// ---------------- fused prep: converts + embed + bias + sentinel + scores-zero + detect
__global__ __launch_bounds__(256) void prep_k(
    const float* __restrict__ w_hh, const float* __restrict__ w_ih,
    const float* __restrict__ wk,   const float* __restrict__ enc,
    const int* __restrict__ ids,
    const float* __restrict__ tok,  const float* __restrict__ pos,
    const float* __restrict__ b_ih, const float* __restrict__ b_hh,
    const unsigned char* __restrict__ pmask,
    u16* __restrict__ whhb, u16* __restrict__ wihb, u16* __restrict__ wkb,
    u16* __restrict__ encb, u16* __restrict__ xbf,
    float* __restrict__ biasf, u64* __restrict__ hbuf,
    float* __restrict__ scores, int* __restrict__ bflag)
{
  __shared__ int sdet;
  const int b = blockIdx.x, tid = threadIdx.x;
  if (b < 8192) {                        // gate-permuted whh / w_ih rows
    const bool ih = b >= 4096;
    const int r = b & 4095;
    const int p = (r & 3) * Hdim + (r >> 2);
    const float4 v = *(const float4*)((ih ? w_ih : w_hh) + (size_t)p * Hdim + tid * 4);
    u16* op = (ih ? wihb : whhb) + (size_t)r * Hdim + tid * 4;
    op[0] = f2b(v.x); op[1] = f2b(v.y); op[2] = f2b(v.z); op[3] = f2b(v.w);
  } else if (b < 9216) {                 // wk
    const size_t i = (size_t)(b - 8192) * 1024 + tid * 4;
    const float4 v = *(const float4*)(wk + i);
    u16* op = wkb + i;
    op[0] = f2b(v.x); op[1] = f2b(v.y); op[2] = f2b(v.z); op[3] = f2b(v.w);
  } else if (b < 11264) {                // enc
    const size_t i = (size_t)(b - 9216) * 1024 + tid * 4;
    const float4 v = *(const float4*)(enc + i);
    u16* op = encb + i;
    op[0] = f2b(v.x); op[1] = f2b(v.y); op[2] = f2b(v.z); op[3] = f2b(v.w);
  } else if (b < 12288) {                // embed
    const int row = b - 11264;
    const int t = row & (Tdim - 1);
    const int id = ids[row];
    const int h0 = tid * 4;
    const float4 a = *(const float4*)(tok + (size_t)id * Hdim + h0);
    const float4 p = *(const float4*)(pos + (size_t)t * Hdim + h0);
    u16* op = xbf + (size_t)row * Hdim + h0;
    op[0] = f2b(a.x + p.x); op[1] = f2b(a.y + p.y); op[2] = f2b(a.z + p.z); op[3] = f2b(a.w + p.w);
  } else if (b < 12292) {                // bias fold (gate-permuted)
    const int n0 = (b - 12288) * 1024 + tid * 4;
#pragma unroll
    for (int j = 0; j < 4; j++) {
      const int n = n0 + j;
      const int p = (n & 3) * Hdim + (n >> 2);
      biasf[n] = b_ih[p] + b_hh[p];
    }
  } else if (b < 12548) {                // hbuf sentinel
    const size_t i = ((size_t)(b - 12292) * 256 + tid) * 4;
    u64x2 s2; s2[0] = SENT; s2[1] = SENT;
    *(u64x2*)(hbuf + i)     = s2;
    *(u64x2*)(hbuf + i + 2) = s2;
  } else if (b < 12804) {                // zero scores (1 MB, for split-K atomics)
    const size_t i = ((size_t)(b - 12548) * 256 + tid) * 4;
    float4 z; z.x = 0.f; z.y = 0.f; z.z = 0.f; z.w = 0.f;
    *(float4*)(scores + i) = z;
  } else {                               // bool dtype detect (1 block)
    if (tid == 0) sdet = 0;
    __syncthreads();
    int loc = 0;
    for (int i = tid; i < 65536; i += 256)
      if ((i & 3) && pmask[i]) loc = 1;
    if (loc) atomicOr(&sdet, 1);
    __syncthreads();
    if (tid == 0) bflag[0] = sdet;
  }
}

// ---------------- small kernels
__device__ __forceinline__ void ln_row_body(const float* __restrict__ in, u16* __restrict__ out,
                                            int row, const float* __restrict__ g,
                                            const float* __restrict__ be){
  const int tid = threadIdx.x;
  const int lane = tid & 63, wid = tid >> 6;
  const float4 x = *(const float4*)(in + (size_t)row * Hdim + tid * 4);
  float s = x.x + x.y + x.z + x.w;
  float q = x.x * x.x + x.y * x.y + x.z * x.z + x.w * x.w;
  for (int o = 32; o; o >>= 1) { s += __shfl_down(s, o, 64); q += __shfl_down(q, o, 64); }
  __shared__ float sm[8];
  if (lane == 0) { sm[wid] = s; sm[4 + wid] = q; }
  __syncthreads();
  const float ts = sm[0] + sm[1] + sm[2] + sm[3];
  const float tq = sm[4] + sm[5] + sm[6] + sm[7];
  const float mean = ts * (1.f / Hdim);
  const float var  = tq * (1.f / Hdim) - mean * mean;
  const float r = rsqrtf(var + 1e-5f);
  const int h0 = tid * 4;
  const float4 gv = *(const float4*)(g + h0);
  const float4 bv = *(const float4*)(be + h0);
  u16* op = out + (size_t)row * Hdim + h0;
  op[0] = f2b((x.x - mean) * r * gv.x + bv.x);
  op[1] = f2b((x.y - mean) * r * gv.y + bv.y);
  op[2] = f2b((x.z - mean) * r * gv.z + bv.z);
  op[3] = f2b((x.w - mean) * r * gv.w + bv.w);
}
__global__ __launch_bounds__(256) void ln_rows(const float* __restrict__ in, u16* __restrict__ out,
                                               const float* __restrict__ g, const float* __restrict__ be){
  ln_row_body(in, out, blockIdx.x, g, be);
}
__global__ __launch_bounds__(256) void ln_qk(const float* __restrict__ qlin, u16* __restrict__ qn,
                                             const float* __restrict__ klin, u16* __restrict__ kn,
                                             const float* __restrict__ g, const float* __restrict__ be){
  const int row = blockIdx.x;
  if (row < 1024) ln_row_body(qlin, qn, row, g, be);
  else            ln_row_body(klin, kn, row - 1024, g, be);
}
__global__ __launch_bounds__(256) void softmax_k(const float* __restrict__ sc, const void* __restrict__ am,
                                                 const int* __restrict__ mflag, u16* __restrict__ w){
  const int row = blockIdx.x, tid = threadIdx.x;
  const int lane = tid & 63, wid = tid >> 6;
  const int b = row >> 7;
  const int bflag = *mflag;
  const float v = sc[(size_t)row * Sdim + tid];
  const bool mk = mask_at(am, (size_t)b * Sdim + tid, bflag);
  const float vm = mk ? v : -10000.0f;
  float mx = vm;
  for (int o = 32; o; o >>= 1) mx = fmaxf(mx, __shfl_down(mx, o, 64));
  __shared__ float sm[8];
  if (lane == 0) sm[wid] = mx;
  __syncthreads();
  mx = fmaxf(fmaxf(sm[0], sm[1]), fmaxf(sm[2], sm[3]));
  const float ex = mk ? expf(vm - mx) : 0.f;
  float ss = ex;
  for (int o = 32; o; o >>= 1) ss += __shfl_down(ss, o, 64);
  if (lane == 0) sm[4 + wid] = ss;
  __syncthreads();
  const float tot = sm[4] + sm[5] + sm[6] + sm[7];
  w[(size_t)row * Sdim + tid] = f2b(ex / (tot + 1e-6f));
}
__global__ __launch_bounds__(256) void transp_k(const u16* __restrict__ kn, u16* __restrict__ knT){
  __shared__ u16 tile[64][65];
  const int b = blockIdx.z, h0 = blockIdx.x * 64, s0 = blockIdx.y * 64;
  const u16* src = kn  + (size_t)b * Sdim * Hdim;
  u16* dst       = knT + (size_t)b * Hdim * Sdim;
  for (int e = threadIdx.x; e < 4096; e += 256) {
    const int r = e >> 6, c = e & 63;
    tile[r][c] = src[(size_t)(s0 + r) * Hdim + h0 + c];
  }
  __syncthreads();
  for (int e = threadIdx.x; e < 4096; e += 256) {
    const int hr = e >> 6, scc = e & 63;
    dst[(size_t)(h0 + hr) * Sdim + s0 + scc] = tile[scc][hr];
  }
}

extern "C" void kernel_launch(void* const* d_in, const int* in_sizes, int n_in,
                              void* d_out, int out_size, void* d_ws, size_t ws_size,
                              hipStream_t stream) {
  const int*   input_ids = (const int*)d_in[0];
  const float* enc   = (const float*)d_in[1];
  const void*  pmask = d_in[2];
  const void*  amask = d_in[3];
  const float* tok  = (const float*)d_in[4];
  const float* pos  = (const float*)d_in[5];
  const float* w_ih = (const float*)d_in[6];
  const float* w_hh = (const float*)d_in[7];
  const float* b_ih = (const float*)d_in[8];
  const float* b_hh = (const float*)d_in[9];
  const float* wq = (const float*)d_in[10];
  const float* bq = (const float*)d_in[11];
  const float* wk = (const float*)d_in[12];
  const float* bk = (const float*)d_in[13];
  const float* wc = (const float*)d_in[14];
  const float* bc = (const float*)d_in[15];
  const float* wo = (const float*)d_in[16];
  const float* bo = (const float*)d_in[17];
  const float* g1  = (const float*)d_in[18];
  const float* be1 = (const float*)d_in[19];
  const float* g2  = (const float*)d_in[20];
  const float* be2 = (const float*)d_in[21];
  float* out = (float*)d_out;

  char* ws = (char*)d_ws;
  size_t off = 0;
  auto alloc = [&](size_t b){ size_t o = off; off += (b + 255) & ~(size_t)255; return o; };
  u16*   whhb  = (u16*)  (ws + alloc((size_t)4096 * 1024 * 2));
  u16*   wihb  = (u16*)  (ws + alloc((size_t)4096 * 1024 * 2));
  u16*   wqb   = (u16*)  (ws + alloc((size_t)1024 * 1024 * 2));
  u16*   wkb   = (u16*)  (ws + alloc((size_t)1024 * 1024 * 2));
  u16*   wcb   = (u16*)  (ws + alloc((size_t)1024 * 2048 * 2));
  float* biasf = (float*)(ws + alloc(4096 * 4));
  u16*   xbf   = (u16*)  (ws + alloc((size_t)1024 * 1024 * 2));
  u16*   encb  = (u16*)  (ws + alloc((size_t)2048 * 1024 * 2));
  u16*   xpre  = (u16*)  (ws + alloc((size_t)1024 * 4096 * 2));
  u16*   hbuf  = (u16*)  (ws + alloc((size_t)Tdim * 64 * 128 * 2));
  u16*   cat   = (u16*)  (ws + alloc((size_t)1024 * 2048 * 2));
  float* qlin  = (float*)(ws + alloc((size_t)1024 * 1024 * 4));
  u16*   qn    = (u16*)  (ws + alloc((size_t)1024 * 1024 * 2));
  float* klin  = (float*)(ws + alloc((size_t)2048 * 1024 * 4));
  u16*   kn    = (u16*)  (ws + alloc((size_t)2048 * 1024 * 2));
  u16*   knT   = (u16*)  (ws + alloc((size_t)2048 * 1024 * 2));
  float* scores= (float*)(ws + alloc((size_t)8 * 128 * 256 * 4));
  u16*   attw  = (u16*)  (ws + alloc((size_t)8 * 128 * 256 * 2));
  float* hlin  = (float*)(ws + alloc((size_t)1024 * 1024 * 4));
  u16*   hid   = (u16*)  (ws + alloc((size_t)1024 * 1024 * 2));
  int*   bflag = (int*)  (ws + alloc(256));
  unsigned char* pmaskb = (unsigned char*)(ws + alloc((size_t)Bdim * Tdim * Vdim));
  const bool havePak = off <= ws_size;
  u16*   wob   = (u16*)  (ws + alloc((size_t)Vdim * Hdim * 2));
  const bool haveWob = off <= ws_size;
  if (!havePak) pmaskb = nullptr;
  if (!haveWob) wob = nullptr;
  (void)in_sizes; (void)n_in; (void)out_size;

  prep_k<<<12805, 256, 0, stream>>>(w_hh, w_ih, wk, enc, input_ids,
      tok, pos, b_ih, b_hh, (const unsigned char*)pmask,
      whhb, wihb, wkb, encb, xbf, biasf, (u64*)hbuf, scores, bflag);

  // x_pre = x @ w_ih_perm.T + (b_ih + b_hh)   -> bf16 (1024 x 4096)
  gemm_bt<u16, false, 0, false><<<dim3(32, 8, 1), 256, 0, stream>>>(
      xbf, 1024, 0, wihb, 1024, 0, xpre, 4096, 0, biasf, nullptr, nullptr, 1024, 1.f);

  // LSTM (0-63, writes hbuf + cat) + k-projection (64-191) + streamers (192-255)
  lstm_plus<<<256, 256, 0, stream>>>(xpre, whhb, hbuf, cat, encb, wkb, klin, bk,
                                     wo, wob, wq, wqb, wc, wcb, pmask, pmaskb, bflag);

  // q = lstm_out @ wq.T + bq ; then LN both q and k in one launch
  gemm_bt<float, false, 0, false><<<dim3(8, 8, 1), 256, 0, stream>>>(
      cat, 2048, 0, wqb, 1024, 0, qlin, 1024, 0, bq, nullptr, nullptr, 1024, 1.f);
  ln_qk<<<3072, 256, 0, stream>>>(qlin, qn, klin, kn, g1, be1);
  transp_k<<<dim3(16, 4, 8), 256, 0, stream>>>(kn, knT);

  // scores = qn @ kn^T * scale — split-K x4 atomicAdd (scores zeroed in prep)
  gemm_sk<<<dim3(2, 4, 8), 256, 0, stream>>>(
      qn, 1024, 131072, kn, 1024, 262144, scores, 256, 32768, 0.015625f);
  softmax_k<<<1024, 256, 0, stream>>>(scores, amask, bflag, attw);
  // ctx = w @ kn  -> right half of cat   (batched)
  gemm_bt<u16, false, 0, false><<<dim3(8, 1, 8), 256, 0, stream>>>(
      attw, 256, 32768, knT, 256, 262144, cat + 1024, 2048, 262144, nullptr, nullptr, nullptr, 256, 1.f);

  // hidden = LN( cat @ wc.T + bc ; g2,be2 )
  gemm_bt<float, false, 0, false><<<dim3(8, 8, 1), 256, 0, stream>>>(
      cat, 2048, 0, wcb, 2048, 0, hlin, 1024, 0, bc, nullptr, nullptr, 2048, 1.f);
  ln_rows<<<1024, 256, 0, stream>>>(hlin, hid, g2, be2);

  // logits = hidden @ wo.T + bo — 128^2 + XCD-bijective swizzle (T1; r2 FETCH=588MB evidence)
  if (wob && pmaskb)
    gemm_bt<float, false, 2, false, true><<<dim3(8, 250, 1), 256, 0, stream>>>(
        hid, 1024, 0, wob, 1024, 0, out, 32000, 0, bo, pmaskb, nullptr, 1024, 1.f);
  else if (wob)
    gemm_bt<float, false, 1, true><<<dim3(8, 250, 1), 256, 0, stream>>>(
        hid, 1024, 0, wob, 1024, 0, out, 32000, 0, bo, pmask, bflag, 1024, 1.f);
  else
    gemm_bt<float, true, 1, true><<<dim3(8, 250, 1), 256, 0, stream>>>(
        hid, 1024, 0, wo, 1024, 0, out, 32000, 0, bo, pmask, bflag, 1024, 1.f);
}